// Round 3
// baseline (4404.239 us; speedup 1.0000x reference)
//
#include <hip/hip_runtime.h>

#define JITF 1e-4f
#define LOG2PIF 1.8378770664093454f

// sizes: D=32, dy=32, M=128, N=128, B=8, T=48
// ws offsets (floats)
#define WZS    0          // 32*4096   zs (k-major: [d][k*128+m])
#define WZS2   131072     // 32*128
#define WKINV  135168     // 32*16384
#define WA     659456     // 32*16384  A[(n*32+d)*128+m]
#define WXW    1183744    // 32*8*128  Xw[(d*8+b)*128+n]
#define WXM    1216512    // 8*32
#define WLLB   1216768    // 8
#define WKLD   1216776    // 128
#define WCNT   1216960    // int counters: cntA at +0, cntC at +32
// out offsets
#define OFM 1048577
#define OFV 1060865

__device__ __forceinline__ float dot4f(const float4 a, const float4 b) {
  return fmaf(a.x, b.x, fmaf(a.y, b.y, fmaf(a.z, b.z, a.w * b.w)));
}

__device__ __forceinline__ void gwait(int* p, int target, int tid) {
  if (tid == 0) {
    while (__hip_atomic_load(p, __ATOMIC_ACQUIRE, __HIP_MEMORY_SCOPE_AGENT) < target)
      __builtin_amdgcn_s_sleep(1);
  }
  __syncthreads();
  __threadfence();
}

__device__ __forceinline__ void gsignal(int* p, int tid) {
  __threadfence();
  __syncthreads();
  if (tid == 0) __hip_atomic_fetch_add(p, 1, __ATOMIC_RELEASE, __HIP_MEMORY_SCOPE_AGENT);
}

// ---------------- Kzz build + SPD sweep inverse + KL partials + U + A ----------------
__global__ __launch_bounds__(512) void k_sweep(
    const float* __restrict__ ips, const float* __restrict__ ls, const float* __restrict__ osc,
    const float* __restrict__ qL, const float* __restrict__ qmu, const float* __restrict__ eu,
    float* __restrict__ zsg, float* __restrict__ zs2g,
    float* __restrict__ Kinvg, float* __restrict__ Ag, float* __restrict__ kld,
    int* cnt)
{
  __shared__ float sm[40064];
  float* A0  = sm;           // [128][129]
  float* A1  = sm + 16512;   // [128][129]
  float* zsT = sm + 33024;   // [32][128]
  float* zs2 = sm + 37120;   // 128
  float* qms = sm + 37248;   // 128
  float* piv = sm + 37376;   // 128
  float* red = sm + 37504;   // 512
  float* Uc  = sm + 38016;   // 8*128
  float* euc = sm + 39040;   // 8*128
  const int d = blockIdx.x, tid = threadIdx.x;
  const float invl = 1.0f / ls[d], oscd = osc[d];

  if (blockIdx.x == 0 && threadIdx.x == 0) { cnt[0] = 0; cnt[32] = 0; }

  for (int l = tid; l < 4096; l += 512) {
    int m = l >> 5, k = l & 31;
    zsT[k*128+m] = ips[(d*128+m)*32+k] * invl;
  }
  if (tid < 128) qms[tid] = qmu[d*128+tid];
  __syncthreads();
  if (tid < 128) {
    float s = 0.f;
    for (int k = 0; k < 32; k++) { float v = zsT[k*128+tid]; s = fmaf(v, v, s); }
    zs2[tid] = s; zs2g[d*128+tid] = s;
  }
  for (int l = tid; l < 4096; l += 512) zsg[d*4096+l] = zsT[l];
  __syncthreads();
  for (int e = tid; e < 16384; e += 512) {
    int i = e >> 7, j = e & 127;
    float dot = 0.f;
    for (int k = 0; k < 32; k++) dot = fmaf(zsT[k*128+i], zsT[k*128+j], dot);
    float d2 = fmaxf(zs2[i] + zs2[j] - 2.f*dot, 0.f);
    A0[i*129+j] = oscd * expf(-0.5f*d2) + (i == j ? JITF : 0.f);
  }
  __syncthreads();

  float* cur = A0; float* nxt = A1;
  for (int k = 0; k < 128; k++) {
    float p = cur[k*129+k];
    float ip = 1.0f / p;
    if (tid == 0) piv[k] = p;
    for (int e = tid; e < 16384; e += 512) {
      int i = e >> 7, j = e & 127;
      float cik = cur[i*129+k];
      float ckj = cur[k*129+j];
      float v;
      if (i == k)      v = (j == k) ? -ip : ckj*ip;
      else if (j == k) v = cik*ip;
      else             v = fmaf(-cik*ip, ckj, cur[i*129+j]);
      nxt[i*129+j] = v;
    }
    __syncthreads();
    float* tmp = cur; cur = nxt; nxt = tmp;
  }
  for (int e = tid; e < 16384; e += 512) { int i = e >> 7, j = e & 127; cur[i*129+j] = -cur[i*129+j]; }
  __syncthreads();
  for (int e = tid; e < 16384; e += 512) Kinvg[d*16384+e] = cur[(e>>7)*129 + (e&127)];
  for (int e = tid; e < 16384; e += 512) nxt[(e>>7)*129 + (e&127)] = qL[d*16384+e];
  __syncthreads();

  red[tid] = (tid < 128) ? logf(piv[tid]) : 0.f;
  __syncthreads();
  for (int s = 256; s > 0; s >>= 1) { if (tid < s) red[tid] += red[tid+s]; __syncthreads(); }
  if (tid == 0) kld[d] = 0.5f * red[0];
  __syncthreads();
  red[tid] = (tid < 128) ? logf(fabsf(nxt[tid*129+tid])) : 0.f;
  __syncthreads();
  for (int s = 256; s > 0; s >>= 1) { if (tid < s) red[tid] += red[tid+s]; __syncthreads(); }
  if (tid == 0) kld[96+d] = red[0];
  __syncthreads();
  {
    float macc = 0.f;
    for (int e = tid; e < 16384; e += 512) {
      int i = e >> 7, j = e & 127;
      macc = fmaf(cur[i*129+j], qms[i]*qms[j], macc);
    }
    red[tid] = macc;
    __syncthreads();
    for (int s = 256; s > 0; s >>= 1) { if (tid < s) red[tid] += red[tid+s]; __syncthreads(); }
    if (tid == 0) kld[64+d] = red[0];
    __syncthreads();
  }
  {
    float tacc = 0.f;
    for (int e = tid; e < 16384; e += 512) {
      int i = e >> 7, k2 = e & 127;
      if (k2 <= i) {
        float w = 0.f;
        for (int m = k2; m < 128; m++) w = fmaf(cur[i*129+m], nxt[m*129+k2], w);
        tacc = fmaf(w, nxt[i*129+k2], tacc);
      }
    }
    red[tid] = tacc;
    __syncthreads();
    for (int s = 256; s > 0; s >>= 1) { if (tid < s) red[tid] += red[tid+s]; __syncthreads(); }
    if (tid == 0) kld[32+d] = red[0];
    __syncthreads();
  }
  for (int c = 0; c < 16; c++) {
    int n0 = c * 8;
    for (int l = tid; l < 1024; l += 512) euc[l] = eu[((n0 + (l>>7))*32 + d)*128 + (l&127)];
    __syncthreads();
    for (int e = tid; e < 1024; e += 512) {
      int nn = e >> 7, m = e & 127;
      float s = qms[m];
      for (int k2 = 0; k2 <= m; k2++) s = fmaf(nxt[m*129+k2], euc[nn*128+k2], s);
      Uc[e] = s;
    }
    __syncthreads();
    for (int e = tid; e < 1024; e += 512) {
      int nn = e >> 7, m = e & 127;
      float s = 0.f;
      for (int mm = 0; mm < 128; mm++) s = fmaf(cur[m*129+mm], Uc[nn*128+mm], s);
      Ag[((n0+nn)*32 + d)*128 + m] = s;
    }
    __syncthreads();
  }
}

// ---------------- t = 0: full per-(n,d) GP predict (unchanged) ----------------
__global__ __launch_bounds__(128) void k_t0gp(
    const float* __restrict__ x0, const float* __restrict__ ls, const float* __restrict__ osc,
    const float* __restrict__ qn, const float* __restrict__ zs, const float* __restrict__ zs2,
    const float* __restrict__ Kinv, const float* __restrict__ A,
    const float* __restrict__ ef, const float* __restrict__ eq, float* __restrict__ Xw)
{
  __shared__ float zssT[4096];
  __shared__ float xqs[8][33];
  __shared__ float xq2s[8];
  __shared__ float Kxzs[8][132];
  __shared__ float T1s[8][132];
  __shared__ float covs[8][9];
  __shared__ float Lc[8][9];
  __shared__ float Arow[128];
  const int n = blockIdx.x >> 5, d = blockIdx.x & 31, tid = threadIdx.x;
  const float invl = 1.0f / ls[d], oscd = osc[d];
  for (int l = tid; l < 4096; l += 128) zssT[l] = zs[d*4096 + l];
  for (int l = tid; l < 256; l += 128) {
    int b = l >> 5, k = l & 31;
    xqs[b][k] = x0[((n*32+d)*8 + b)*32 + k] * invl;
  }
  Arow[tid] = A[(n*32+d)*128 + tid];
  __syncthreads();
  if (tid < 8) {
    float s = 0.f;
#pragma unroll
    for (int k = 0; k < 32; k++) { float v = xqs[tid][k]; s = fmaf(v, v, s); }
    xq2s[tid] = s;
  }
  __syncthreads();
  {
    float z2m = zs2[d*128 + tid];
#pragma unroll
    for (int b = 0; b < 8; b++) {
      float dot = 0.f;
#pragma unroll
      for (int k = 0; k < 32; k++) dot = fmaf(xqs[b][k], zssT[k*128 + tid], dot);
      Kxzs[b][tid] = oscd * expf(-0.5f * fmaxf(xq2s[b] + z2m - 2.f*dot, 0.f));
    }
  }
  __syncthreads();
  {
    float a[8] = {0.f,0.f,0.f,0.f,0.f,0.f,0.f,0.f};
    const float* kp = Kinv + d*16384 + tid;
    for (int mm = 0; mm < 128; mm++) {
      float kv = kp[mm*128];
#pragma unroll
      for (int b = 0; b < 8; b++) a[b] = fmaf(Kxzs[b][mm], kv, a[b]);
    }
#pragma unroll
    for (int b = 0; b < 8; b++) T1s[b][tid] = a[b];
  }
  __syncthreads();
  if (tid < 64) {
    int b = tid >> 3, c = tid & 7;
    float dot = 0.f;
#pragma unroll
    for (int k = 0; k < 32; k++) dot = fmaf(xqs[b][k], xqs[c][k], dot);
    float kxx = oscd * expf(-0.5f * fmaxf(xq2s[b] + xq2s[c] - 2.f*dot, 0.f));
    float s0 = 0.f, s1 = 0.f;
    for (int m = 0; m < 128; m += 2) {
      s0 = fmaf(T1s[b][m], Kxzs[c][m], s0);
      s1 = fmaf(T1s[b][m+1], Kxzs[c][m+1], s1);
    }
    covs[b][c] = kxx - (s0+s1) + (b == c ? JITF : 0.f);
  }
  __syncthreads();
  if (tid == 0) {
    for (int a = 0; a < 8; a++) {
      float s = covs[a][a];
      for (int k = 0; k < a; k++) s -= Lc[a][k]*Lc[a][k];
      float la = sqrtf(s);
      Lc[a][a] = la;
      for (int i = a+1; i < 8; i++) {
        float s2 = covs[i][a];
        for (int k = 0; k < a; k++) s2 -= Lc[i][k]*Lc[a][k];
        Lc[i][a] = s2 / la;
      }
      for (int c = a+1; c < 8; c++) Lc[a][c] = 0.f;
    }
  }
  __syncthreads();
  if (tid < 8) {
    int b = tid;
    float m0 = 0.f, m1 = 0.f;
    for (int m = 0; m < 128; m += 2) {
      m0 = fmaf(Kxzs[b][m], Arow[m], m0);
      m1 = fmaf(Kxzs[b][m+1], Arow[m+1], m1);
    }
    float f = m0 + m1;
#pragma unroll
    for (int c = 0; c < 8; c++) f = fmaf(Lc[b][c], ef[(n*32+d)*8 + c], f);
    float X = f + eq[(b*128+n)*32 + d] * sqrtf(qn[d]);
    Xw[(d*8+b)*128 + n] = X;
  }
}

// ---------------- cooperative scan: 32 d-blocks + 8 b-blocks, 1024 thr ----------------
__global__ __launch_bounds__(1024) void k_scan(
    const float* __restrict__ ls, const float* __restrict__ osc,
    const float* __restrict__ qn, const float* __restrict__ rn,
    const float* __restrict__ y,
    const float* __restrict__ ef, const float* __restrict__ eq, const float* __restrict__ er,
    const float* __restrict__ zsg, const float* __restrict__ zs2g,
    const float* __restrict__ Kinvg, const float* __restrict__ Ag,
    float* Xw, float* xm, float* llb, const float* __restrict__ kld,
    float* out, int* cnt)
{
  __shared__ float sm[28448];
  const int blk = blockIdx.x, tid = threadIdx.x;
  int* cntA = cnt;
  int* cntC = cnt + 32;

  if (blk < 32) {
    // ================= d-role =================
    const int d = blk;
    const float invl = 1.0f/ls[d], oscd = osc[d], qsd = sqrtf(qn[d]);
    float* zsT  = sm;          // [32][128]
    float* zs2S = sm + 4096;   // 128
    float* xqS  = sm + 4224;   // [8][36]
    float* xq2S = sm + 4512;   // 8
    float* KxzS = sm + 4520;   // [8][132]
    float* T1f  = sm + 5576;   // [8][132]
    float* Pp   = sm + 6632;   // [4][1056]
    float* Pm   = sm + 10856;  // [8][1184]
    float* efS  = sm + 20328;  // [128][9]
    float* eqS  = sm + 21480;  // [8][132]
    float* LcS  = sm + 22536;  // [8][9]
    float* covS = sm + 22608;  // [8][9]
    const float4* zsT4  = (const float4*)zsT;
    const float4* zs2S4 = (const float4*)zs2S;
    float4* KxzS4 = (float4*)KxzS;
    const float4* T1f4 = (const float4*)T1f;
    float4* Pp4 = (float4*)Pp;
    const float4* Kg4 = (const float4*)(Kinvg + d*16384);
    const float4* Ag4 = (const float4*)Ag;
    const float4* ef4 = (const float4*)ef;

    for (int l = tid; l < 4096; l += 1024) zsT[l] = zsg[d*4096+l];
    if (tid < 128) zs2S[tid] = zs2g[d*128+tid];
    __syncthreads();

    for (int t = 1; t < 48; t++) {
      gwait(cntC, 8*t, tid);
      if (tid < 256) { int b = tid>>5, k = tid&31; xqS[b*36+k] = xm[b*32+k]*invl; }
      __syncthreads();
      if (tid < 8) {
        float s = 0.f;
#pragma unroll
        for (int k = 0; k < 32; k++) { float v = xqS[tid*36+k]; s = fmaf(v,v,s); }
        xq2S[tid] = s;
      }
      __syncthreads();
      if (tid < 256) {
        int b = tid>>5, mq = tid&31;
        float ax=0.f, ay=0.f, az=0.f, aw=0.f;
#pragma unroll
        for (int k = 0; k < 32; k++) {
          float xv = xqS[b*36+k];
          float4 z = zsT4[k*32+mq];
          ax = fmaf(xv,z.x,ax); ay = fmaf(xv,z.y,ay); az = fmaf(xv,z.z,az); aw = fmaf(xv,z.w,aw);
        }
        float xb = xq2S[b];
        float4 z2 = zs2S4[mq];
        float4 r;
        r.x = oscd*expf(-0.5f*fmaxf(xb+z2.x-2.f*ax, 0.f));
        r.y = oscd*expf(-0.5f*fmaxf(xb+z2.y-2.f*ay, 0.f));
        r.z = oscd*expf(-0.5f*fmaxf(xb+z2.z-2.f*az, 0.f));
        r.w = oscd*expf(-0.5f*fmaxf(xb+z2.w-2.f*aw, 0.f));
        KxzS4[b*33+mq] = r;
      }
      __syncthreads();
      {
        int w = tid >> 6;
        if (w < 4) {
          // T1 = Kxz @ Kinv (global Kinv, f4 coalesced), tile 4m x 4b, kk=4 splits of mm
          int kk = w, lane = tid&63, mq = lane>>1, bq = lane&1, b0 = bq*4;
          float4 a0 = {0,0,0,0}, a1 = {0,0,0,0}, a2 = {0,0,0,0}, a3 = {0,0,0,0};
          for (int mm = kk*32; mm < kk*32+32; mm++) {
            float4 kv = Kg4[mm*32+mq];
            float k0 = KxzS[(b0+0)*132+mm];
            float k1 = KxzS[(b0+1)*132+mm];
            float k2 = KxzS[(b0+2)*132+mm];
            float k3 = KxzS[(b0+3)*132+mm];
            a0.x = fmaf(kv.x,k0,a0.x); a0.y = fmaf(kv.y,k0,a0.y); a0.z = fmaf(kv.z,k0,a0.z); a0.w = fmaf(kv.w,k0,a0.w);
            a1.x = fmaf(kv.x,k1,a1.x); a1.y = fmaf(kv.y,k1,a1.y); a1.z = fmaf(kv.z,k1,a1.z); a1.w = fmaf(kv.w,k1,a1.w);
            a2.x = fmaf(kv.x,k2,a2.x); a2.y = fmaf(kv.y,k2,a2.y); a2.z = fmaf(kv.z,k2,a2.z); a2.w = fmaf(kv.w,k2,a2.w);
            a3.x = fmaf(kv.x,k3,a3.x); a3.y = fmaf(kv.y,k3,a3.y); a3.z = fmaf(kv.z,k3,a3.z); a3.w = fmaf(kv.w,k3,a3.w);
          }
          Pp4[kk*264 + (b0+0)*33 + mq] = a0;
          Pp4[kk*264 + (b0+1)*33 + mq] = a1;
          Pp4[kk*264 + (b0+2)*33 + mq] = a2;
          Pp4[kk*264 + (b0+3)*33 + mq] = a3;
        } else if (w < 12) {
          // mean[n][b] = Kxz @ A (global A), tile 4n x 4b, kk=8 splits of m
          int idx = tid-256, kk = idx>>6, lane = idx&63, nq = lane>>1, bq = lane&1;
          int n0 = nq*4, b0 = bq*4;
          float acc[4][4];
#pragma unroll
          for (int r = 0; r < 4; r++)
#pragma unroll
            for (int s = 0; s < 4; s++) acc[r][s] = 0.f;
#pragma unroll
          for (int mqi = 0; mqi < 4; mqi++) {
            int m4 = kk*4+mqi;
            float4 ar[4], kx[4];
#pragma unroll
            for (int r = 0; r < 4; r++) ar[r] = Ag4[((n0+r)*32+d)*32 + m4];
#pragma unroll
            for (int s = 0; s < 4; s++) kx[s] = KxzS4[(b0+s)*33 + m4];
#pragma unroll
            for (int r = 0; r < 4; r++)
#pragma unroll
              for (int s = 0; s < 4; s++) acc[r][s] += dot4f(ar[r], kx[s]);
          }
#pragma unroll
          for (int r = 0; r < 4; r++)
#pragma unroll
            for (int s = 0; s < 4; s++) Pm[kk*1184 + (n0+r)*9 + (b0+s)] = acc[r][s];
        } else {
          // stage ef, eq slices for this (t, d)
          int idx = tid-768;
          {
            int n = idx>>1, cq = idx&1;
            float4 e = ef4[((t*128+n)*32+d)*2 + cq];
            int o = n*9+cq*4;
            efS[o] = e.x; efS[o+1] = e.y; efS[o+2] = e.z; efS[o+3] = e.w;
          }
          {
            int b = idx>>5, nq = idx&31;
#pragma unroll
            for (int r = 0; r < 4; r++)
              eqS[b*132+nq*4+r] = eq[((t*8+b)*128 + nq*4+r)*32 + d];
          }
        }
      }
      __syncthreads();
      { // T1 combine
        int b = tid>>7, m = tid&127;
        T1f[b*132+m] = Pp[b*132+m] + Pp[1056+b*132+m] + Pp[2112+b*132+m] + Pp[3168+b*132+m];
      }
      __syncthreads();
      if (tid < 64) { // cov
        int b = tid>>3, c = tid&7;
        float4 s4 = {0,0,0,0};
        for (int mq = 0; mq < 32; mq++) {
          float4 t1 = T1f4[b*33+mq];
          float4 kx = KxzS4[c*33+mq];
          s4.x = fmaf(t1.x,kx.x,s4.x); s4.y = fmaf(t1.y,kx.y,s4.y);
          s4.z = fmaf(t1.z,kx.z,s4.z); s4.w = fmaf(t1.w,kx.w,s4.w);
        }
        float sc = (s4.x+s4.y)+(s4.z+s4.w);
        float dt = 0.f;
#pragma unroll
        for (int k = 0; k < 32; k++) dt = fmaf(xqS[b*36+k], xqS[c*36+k], dt);
        float kxx = oscd*expf(-0.5f*fmaxf(xq2S[b]+xq2S[c]-2.f*dt, 0.f));
        covS[b*9+c] = kxx - sc + (b==c ? JITF : 0.f);
      }
      __syncthreads();
      if (tid == 0) { // chol 8x8
        for (int a = 0; a < 8; a++) {
          float s = covS[a*9+a];
          for (int k = 0; k < a; k++) s -= LcS[a*9+k]*LcS[a*9+k];
          float la = sqrtf(s);
          LcS[a*9+a] = la;
          for (int i2 = a+1; i2 < 8; i2++) {
            float s2 = covS[i2*9+a];
            for (int k = 0; k < a; k++) s2 -= LcS[i2*9+k]*LcS[a*9+k];
            LcS[i2*9+a] = s2/la;
          }
        }
      }
      __syncthreads();
      { // f = mean + Lc@ef + eq*qsd -> Xw
        int b = tid>>7, n = tid&127;
        float mv = 0.f;
#pragma unroll
        for (int kk = 0; kk < 8; kk++) mv += Pm[kk*1184 + n*9 + b];
        for (int c = 0; c <= b; c++) mv = fmaf(LcS[b*9+c], efS[n*9+c], mv);
        mv = fmaf(eqS[b*132+n], qsd, mv);
        Xw[(d*8+b)*128+n] = mv;
      }
      gsignal(cntA, tid);
    }
    gwait(cntC, 384, tid);
  } else {
    // ================= b-role =================
    const int b = blk - 32;
    float* XT     = sm;           // [32][132]
    float* Pp2    = sm + 4224;    // [16][1088]
    float* Ps     = sm + 21632;   // [32][36]
    float* Sinvs  = sm + 22784;   // [32][33]
    float* Zs     = sm + 23840;   // [32][33]
    float* taperS = sm + 24896;   // 1024
    float* mersS  = sm + 25920;   // [48][32]
    float* rowP   = sm + 27456;   // [2][2][36]
    float* colP   = sm + 27600;   // [2][2][36]
    float* detS   = sm + 27744;   // 16
    float* XmsS   = sm + 27760;   // 32
    float* residS = sm + 27792;   // 32
    float* alphS  = sm + 27824;   // 32
    float* miS    = sm + 27856;   // 32
    float* rsdS   = sm + 27888;   // 32
    float* rnS    = sm + 27920;   // 32
    float* redS   = sm + 27952;   // [32][9]
    float4* XT4 = (float4*)XT;
    const float4* Ps4 = (const float4*)Ps;
    const float4* Xw4 = (const float4*)Xw;
    const float4* er4 = (const float4*)er;

    { // taper
      int l = tid;
      if (l < 1024) {
        int i = l >> 5, j = l & 31;
        int ad = i - j; if (ad < 0) ad = -ad;
        int dist = (ad < 32 - ad) ? ad : (32 - ad);
        double z = (double)dist / 5.0;
        double z2 = z*z, z3 = z2*z, z4 = z3*z, z5 = z4*z;
        double gval;
        if (z < 1.0) gval = 1.0 - (5.0/3.0)*z2 + (5.0/8.0)*z3 + 0.5*z4 - 0.25*z5;
        else if (z < 2.0) gval = 4.0 - 5.0*z + (5.0/3.0)*z2 + (5.0/8.0)*z3 - 0.5*z4 + (1.0/12.0)*z5 - 2.0/(3.0*z);
        else gval = 0.0;
        taperS[l] = (float)gval;
      }
    }
    if (tid < 32) { rnS[tid] = rn[tid]; rsdS[tid] = sqrtf(rn[tid]); }
    if (tid < 384) { // mers for all t
      int tt = tid>>3, jq = tid&7;
      float sx=0.f, sy=0.f, sz=0.f, sw=0.f;
      for (int n = 0; n < 128; n++) {
        float4 e = er4[((tt*8+b)*128+n)*8 + jq];
        sx += e.x; sy += e.y; sz += e.z; sw += e.w;
      }
      int o = tt*32+jq*4;
      mersS[o]   = sx*(1.f/128.f);
      mersS[o+1] = sy*(1.f/128.f);
      mersS[o+2] = sz*(1.f/128.f);
      mersS[o+3] = sw*(1.f/128.f);
    }
    __syncthreads();

    float llacc = 0.f;
    const int i = tid >> 5, j = tid & 31;
    for (int t = 0; t < 48; t++) {
      if (t > 0) gwait(cntA, 32*t, tid);
      { // load Xw -> XT (transposed, f4)
        int dd = tid>>5, nq = tid&31;
        XT4[dd*33+nq] = Xw4[(dd*8+b)*32 + nq];
      }
      __syncthreads();
      if (tid < 256) { // row partial sums
        int ii = tid>>3, c = tid&7;
        float4 s = {0,0,0,0};
#pragma unroll
        for (int q = 0; q < 4; q++) {
          float4 v = XT4[ii*33 + c*4 + q];
          s.x += v.x; s.y += v.y; s.z += v.z; s.w += v.w;
        }
        redS[ii*9+c] = (s.x+s.y)+(s.z+s.w);
      }
      __syncthreads();
      if (tid < 32) {
        float s = 0.f;
#pragma unroll
        for (int c = 0; c < 8; c++) s += redS[tid*9+c];
        XmsS[tid] = s*(1.f/128.f);
      }
      __syncthreads();
      { // center
        int ii = tid>>5, nq = tid&31;
        float4 v = XT4[ii*33+nq];
        float mu = XmsS[ii];
        v.x -= mu; v.y -= mu; v.z -= mu; v.w -= mu;
        XT4[ii*33+nq] = v;
      }
      __syncthreads();
      { // P partials: tile 4x4, kk=16 over n
        int kk = tid>>6, tile = tid&63, iq = tile>>3, jq = tile&7;
        float acc[4][4];
#pragma unroll
        for (int r = 0; r < 4; r++)
#pragma unroll
          for (int s = 0; s < 4; s++) acc[r][s] = 0.f;
#pragma unroll
        for (int q = 0; q < 2; q++) {
          int nq = kk*2+q;
          float4 av[4], bv[4];
#pragma unroll
          for (int r = 0; r < 4; r++) av[r] = XT4[(iq*4+r)*33 + nq];
#pragma unroll
          for (int s = 0; s < 4; s++) bv[s] = XT4[(jq*4+s)*33 + nq];
#pragma unroll
          for (int r = 0; r < 4; r++)
#pragma unroll
            for (int s = 0; s < 4; s++) acc[r][s] += dot4f(av[r], bv[s]);
        }
#pragma unroll
        for (int r = 0; r < 4; r++)
#pragma unroll
          for (int s = 0; s < 4; s++) Pp2[kk*1088 + tile*17 + r*4+s] = acc[r][s];
      }
      __syncthreads();
      float val;
      { // P combine + taper + S init (register)
        int tile = (i>>2)*8 + (j>>2), off = (i&3)*4 + (j&3);
        float pv = 0.f;
#pragma unroll
        for (int kk = 0; kk < 16; kk++) pv += Pp2[kk*1088 + tile*17 + off];
        pv *= taperS[i*32+j]*(1.f/127.f);
        Ps[i*36+j] = pv;
        val = pv + ((i==j) ? rnS[i] : 0.f);
      }
      // 2x2-pivot block sweep of S in registers -> -Sinv
#pragma unroll 1
      for (int kb = 0; kb < 16; kb++) {
        int k0 = kb*2, k1 = k0+1, par = (kb&1)*72;
        if (i == k0) rowP[par + j]      = val;
        if (i == k1) rowP[par + 36 + j] = val;
        if (j == k0) colP[par + i]      = val;
        if (j == k1) colP[par + 36 + i] = val;
        __syncthreads();
        float a  = rowP[par + k0];
        float bb = rowP[par + k1];
        float c  = rowP[par + 36 + k1];
        float det = fmaf(a, c, -bb*bb);
        float idet = 1.0f/det;
        float ci0 = colP[par + i], ci1 = colP[par + 36 + i];
        float r0j = rowP[par + j], r1j = rowP[par + 36 + j];
        float w0 = (ci0*c - ci1*bb)*idet;
        float w1 = (ci1*a - ci0*bb)*idet;
        float v0 = (c*r0j - bb*r1j)*idet;
        float v1 = (a*r1j - bb*r0j)*idet;
        float nv = val - w0*r0j - w1*r1j;
        if (i == k0) nv = v0;
        if (i == k1) nv = v1;
        if (j == k0) nv = w0;
        if (j == k1) nv = w1;
        if (i == k0 && j == k0) nv = -c*idet;
        if (i == k0 && j == k1) nv =  bb*idet;
        if (i == k1 && j == k0) nv =  bb*idet;
        if (i == k1 && j == k1) nv = -a*idet;
        val = nv;
        if (tid == 0) detS[kb] = det;
      }
      Sinvs[i*33+j] = -val;
      if (tid < 32) {
        float rs = y[(b*48+t)*32+tid] - XmsS[tid];
        residS[tid] = rs;
        miS[tid] = fmaf(mersS[t*32+tid], rsdS[tid], rs);
      }
      __syncthreads();
      if (tid < 256) { // Z = Sinv @ P partials (kk=4 over k)
        int kk = tid>>6, tile = tid&63, iq = tile>>3, jq = tile&7;
        float4 az[4];
#pragma unroll
        for (int r = 0; r < 4; r++) { az[r].x=0.f; az[r].y=0.f; az[r].z=0.f; az[r].w=0.f; }
        for (int k = kk*8; k < kk*8+8; k++) {
          float4 pr = Ps4[k*9+jq];
#pragma unroll
          for (int r = 0; r < 4; r++) {
            float a = Sinvs[(iq*4+r)*33+k];
            az[r].x = fmaf(a,pr.x,az[r].x); az[r].y = fmaf(a,pr.y,az[r].y);
            az[r].z = fmaf(a,pr.z,az[r].z); az[r].w = fmaf(a,pr.w,az[r].w);
          }
        }
#pragma unroll
        for (int r = 0; r < 4; r++) {
          int o = kk*1088 + tile*17 + r*4;
          Pp2[o] = az[r].x; Pp2[o+1] = az[r].y; Pp2[o+2] = az[r].z; Pp2[o+3] = az[r].w;
        }
      } else if (tid < 288) { // alpha = Sinv @ resid
        int ii = tid-256;
        float s = 0.f;
#pragma unroll
        for (int k = 0; k < 32; k++) s = fmaf(Sinvs[ii*33+k], residS[k], s);
        alphS[ii] = s;
      }
      __syncthreads();
      { // Z combine
        int tile = (i>>2)*8 + (j>>2), off = (i&3)*4 + (j&3);
        Zs[i*33+j] = Pp2[tile*17+off] + Pp2[1088+tile*17+off] + Pp2[2176+tile*17+off] + Pp2[3264+tile*17+off];
      }
      __syncthreads();
      if (tid < 32) { // posterior mean + var
        int ii = tid;
        float xs = 0.f, fvv = 0.f;
#pragma unroll
        for (int jj = 0; jj < 32; jj++) {
          float z = Zs[jj*33+ii];
          xs = fmaf(z, miS[jj], xs);
          fvv = fmaf(z, Ps[jj*36+ii], fvv);
        }
        float xmp = XmsS[ii] + xs;
        out[OFM + (b*48+t)*32 + ii] = xmp;
        out[OFV + (b*48+t)*32 + ii] = Ps[ii*36+ii] - fvv;
        xm[b*32+ii] = xmp;
      } else if (tid == 64) { // ll
        float quad = 0.f;
#pragma unroll
        for (int k = 0; k < 32; k++) quad = fmaf(residS[k], alphS[k], quad);
        float ld = 0.f;
#pragma unroll
        for (int s = 0; s < 16; s++) ld += logf(detS[s]);
        llacc += -0.5f*(32.f*LOG2PIF + ld + quad);
        if (t == 47) llb[b] = llacc;
      }
      gsignal(cntC, tid);
    }
    gwait(cntC, 384, tid);
  }

  // ---------------- epilogue: x_final broadcast + elbo ----------------
  if (tid < 256) sm[tid] = xm[tid];
  __syncthreads();
  for (int v = blk*1024 + tid; v < 1048576; v += 40960)
    out[1 + v] = sm[v & 255];
  if (blk == 32 && tid == 0) {
    double ll = 0.0;
    for (int i2 = 0; i2 < 8; i2++) ll += (double)llb[i2];
    double ldK = 0.0, tr = 0.0, mah = 0.0, ldS = 0.0;
    for (int d2 = 0; d2 < 32; d2++) {
      ldK += (double)kld[d2];
      tr  += (double)kld[32+d2];
      mah += (double)kld[64+d2];
      ldS += (double)kld[96+d2];
    }
    double klv = 0.5*(tr + mah - 4096.0 + 2.0*ldK - 2.0*ldS);
    out[0] = (float)(ll - klv/100000.0);
  }
}

extern "C" void kernel_launch(void* const* d_in, const int* in_sizes, int n_in,
                              void* d_out, int out_size, void* d_ws, size_t ws_size,
                              hipStream_t stream) {
  const float* ips = (const float*)d_in[0];
  const float* ls  = (const float*)d_in[2];
  const float* osc = (const float*)d_in[3];
  const float* qmu = (const float*)d_in[4];
  const float* qL  = (const float*)d_in[5];
  const float* qn  = (const float*)d_in[6];
  const float* rn  = (const float*)d_in[7];
  const float* x0  = (const float*)d_in[8];
  const float* y   = (const float*)d_in[9];
  const float* eu  = (const float*)d_in[10];
  const float* ef  = (const float*)d_in[11];
  const float* eq  = (const float*)d_in[12];
  const float* er  = (const float*)d_in[13];
  float* out = (float*)d_out;
  float* ws  = (float*)d_ws;

  float* w_zs   = ws + WZS;
  float* w_zs2  = ws + WZS2;
  float* w_kinv = ws + WKINV;
  float* w_A    = ws + WA;
  float* w_Xw   = ws + WXW;
  float* w_xm   = ws + WXM;
  float* w_llb  = ws + WLLB;
  float* w_kld  = ws + WKLD;
  int*   w_cnt  = (int*)(ws + WCNT);

  k_sweep<<<32, 512, 0, stream>>>(ips, ls, osc, qL, qmu, eu, w_zs, w_zs2, w_kinv, w_A, w_kld, w_cnt);
  k_t0gp<<<4096, 128, 0, stream>>>(x0, ls, osc, qn, w_zs, w_zs2, w_kinv, w_A, ef, eq, w_Xw);
  void* args[] = { (void*)&ls, (void*)&osc, (void*)&qn, (void*)&rn, (void*)&y,
                   (void*)&ef, (void*)&eq, (void*)&er, (void*)&w_zs, (void*)&w_zs2,
                   (void*)&w_kinv, (void*)&w_A, (void*)&w_Xw, (void*)&w_xm, (void*)&w_llb,
                   (void*)&w_kld, (void*)&out, (void*)&w_cnt };
  hipLaunchCooperativeKernel((void*)k_scan, dim3(40), dim3(1024), args, 0, stream);
}

// Round 4
// 2353.240 us; speedup vs baseline: 1.8716x; 1.8716x over previous
//
#include <hip/hip_runtime.h>

#define JITF 1e-4f
#define LOG2PIF 1.8378770664093454f

// sizes: D=32, dy=32, M=128, N=128, B=8, T=48
// ws offsets (floats)
#define WZS    0          // 32*4096   zs (k-major: [d][k*128+m])
#define WZS2   131072     // 32*128
#define WKINV  135168     // 32*16384  Kinv[d][i*128+j] (symmetric)
#define WA     659456     // 32*16384  A[(n*32+d)*128+m]
#define WU     1183744    // 128*32*128 U[(n*32+d)*128+m]
#define WXW    1708032    // 32*8*128  Xw[(d*8+b)*128+n]
#define WXM    1740800    // 8*32
#define WLLB   1741056    // 8
#define WKLD   1741088    // 128
#define WCNT   1741248    // int counters: cntA at +0, cntC at +32
// out offsets
#define OFM 1048577
#define OFV 1060865

__device__ __forceinline__ float dot4f(const float4 a, const float4 b) {
  return fmaf(a.x, b.x, fmaf(a.y, b.y, fmaf(a.z, b.z, a.w * b.w)));
}
__device__ __forceinline__ float aloadf(const float* p) {
  return __hip_atomic_load((float*)p, __ATOMIC_RELAXED, __HIP_MEMORY_SCOPE_AGENT);
}
__device__ __forceinline__ void astoref(float* p, float v) {
  __hip_atomic_store(p, v, __ATOMIC_RELAXED, __HIP_MEMORY_SCOPE_AGENT);
}
__device__ __forceinline__ unsigned long long aloadu(const unsigned long long* p) {
  return __hip_atomic_load((unsigned long long*)p, __ATOMIC_RELAXED, __HIP_MEMORY_SCOPE_AGENT);
}
// RELAXED poll (no per-iteration cache invalidate), single ACQUIRE on success.
__device__ __forceinline__ void gwait(int* p, int target, int tid) {
  if (tid == 0) {
    while (__hip_atomic_load(p, __ATOMIC_RELAXED, __HIP_MEMORY_SCOPE_AGENT) < target)
      __builtin_amdgcn_s_sleep(2);
    (void)__hip_atomic_load(p, __ATOMIC_ACQUIRE, __HIP_MEMORY_SCOPE_AGENT);
  }
  __syncthreads();
}
// __syncthreads drains vmcnt -> all this block's agent-scope stores are at the
// coherence point before tid0's release-add.
__device__ __forceinline__ void gsignal(int* p, int tid) {
  __syncthreads();
  if (tid == 0) __hip_atomic_fetch_add(p, 1, __ATOMIC_RELEASE, __HIP_MEMORY_SCOPE_AGENT);
}

// ---------------- Kzz build + SPD sweep inverse + KL partials ----------------
__global__ __launch_bounds__(512) void k_sweep(
    const float* __restrict__ ips, const float* __restrict__ ls, const float* __restrict__ osc,
    const float* __restrict__ qL, const float* __restrict__ qmu,
    float* __restrict__ zsg, float* __restrict__ zs2g,
    float* __restrict__ Kinvg, float* __restrict__ kld, int* cnt)
{
  __shared__ float sm[38016];
  float* A0  = sm;           // [128][129]
  float* A1  = sm + 16512;   // [128][129]
  float* zsT = sm + 33024;   // [32][128]
  float* zs2 = sm + 37120;   // 128
  float* qms = sm + 37248;   // 128
  float* piv = sm + 37376;   // 128
  float* red = sm + 37504;   // 512
  const int d = blockIdx.x, tid = threadIdx.x;
  const float invl = 1.0f / ls[d], oscd = osc[d];

  if (blockIdx.x == 0 && threadIdx.x == 0) { cnt[0] = 0; cnt[32] = 0; }

  for (int l = tid; l < 4096; l += 512) {
    int m = l >> 5, k = l & 31;
    zsT[k*128+m] = ips[(d*128+m)*32+k] * invl;
  }
  if (tid < 128) qms[tid] = qmu[d*128+tid];
  __syncthreads();
  if (tid < 128) {
    float s = 0.f;
    for (int k = 0; k < 32; k++) { float v = zsT[k*128+tid]; s = fmaf(v, v, s); }
    zs2[tid] = s; zs2g[d*128+tid] = s;
  }
  for (int l = tid; l < 4096; l += 512) zsg[d*4096+l] = zsT[l];
  __syncthreads();
  for (int e = tid; e < 16384; e += 512) {
    int i = e >> 7, j = e & 127;
    float dot = 0.f;
    for (int k = 0; k < 32; k++) dot = fmaf(zsT[k*128+i], zsT[k*128+j], dot);
    float d2 = fmaxf(zs2[i] + zs2[j] - 2.f*dot, 0.f);
    A0[i*129+j] = oscd * expf(-0.5f*d2) + (i == j ? JITF : 0.f);
  }
  __syncthreads();

  float* cur = A0; float* nxt = A1;
  for (int k = 0; k < 128; k++) {
    float p = cur[k*129+k];
    float ip = 1.0f / p;
    if (tid == 0) piv[k] = p;
    for (int e = tid; e < 16384; e += 512) {
      int i = e >> 7, j = e & 127;
      float cik = cur[i*129+k];
      float ckj = cur[k*129+j];
      float v;
      if (i == k)      v = (j == k) ? -ip : ckj*ip;
      else if (j == k) v = cik*ip;
      else             v = fmaf(-cik*ip, ckj, cur[i*129+j]);
      nxt[i*129+j] = v;
    }
    __syncthreads();
    float* tmp = cur; cur = nxt; nxt = tmp;
  }
  for (int e = tid; e < 16384; e += 512) { int i = e >> 7, j = e & 127; cur[i*129+j] = -cur[i*129+j]; }
  __syncthreads();
  for (int e = tid; e < 16384; e += 512) Kinvg[d*16384+e] = cur[(e>>7)*129 + (e&127)];
  for (int e = tid; e < 16384; e += 512) nxt[(e>>7)*129 + (e&127)] = qL[d*16384+e];
  __syncthreads();

  red[tid] = (tid < 128) ? logf(piv[tid]) : 0.f;
  __syncthreads();
  for (int s = 256; s > 0; s >>= 1) { if (tid < s) red[tid] += red[tid+s]; __syncthreads(); }
  if (tid == 0) kld[d] = 0.5f * red[0];
  __syncthreads();
  red[tid] = (tid < 128) ? logf(fabsf(nxt[tid*129+tid])) : 0.f;
  __syncthreads();
  for (int s = 256; s > 0; s >>= 1) { if (tid < s) red[tid] += red[tid+s]; __syncthreads(); }
  if (tid == 0) kld[96+d] = red[0];
  __syncthreads();
  {
    float macc = 0.f;
    for (int e = tid; e < 16384; e += 512) {
      int i = e >> 7, j = e & 127;
      macc = fmaf(cur[i*129+j], qms[i]*qms[j], macc);
    }
    red[tid] = macc;
    __syncthreads();
    for (int s = 256; s > 0; s >>= 1) { if (tid < s) red[tid] += red[tid+s]; __syncthreads(); }
    if (tid == 0) kld[64+d] = red[0];
    __syncthreads();
  }
  {
    float tacc = 0.f;
    for (int e = tid; e < 16384; e += 512) {
      int i = e >> 7, k2 = e & 127;
      if (k2 <= i) {
        float w = 0.f;
        for (int m = k2; m < 128; m++) w = fmaf(cur[i*129+m], nxt[m*129+k2], w);
        tacc = fmaf(w, nxt[i*129+k2], tacc);
      }
    }
    red[tid] = tacc;
    __syncthreads();
    for (int s = 256; s > 0; s >>= 1) { if (tid < s) red[tid] += red[tid+s]; __syncthreads(); }
    if (tid == 0) kld[32+d] = red[0];
  }
}

// ---------------- U = q_mu + q_L @ eps_u ----------------
__global__ __launch_bounds__(128) void k_U(
    const float* __restrict__ qL, const float* __restrict__ qmu, const float* __restrict__ eu,
    float* __restrict__ U)
{
  __shared__ float qLs[128][129];
  __shared__ float eus[128];
  const int d = blockIdx.x >> 2, nc = blockIdx.x & 3, tid = threadIdx.x;
  for (int l = tid; l < 16384; l += 128) qLs[l >> 7][l & 127] = qL[d * 16384 + l];
  __syncthreads();
  const float qm = qmu[d * 128 + tid];
  for (int nn = 0; nn < 32; nn++) {
    int n = nc * 32 + nn;
    eus[tid] = eu[(n * 32 + d) * 128 + tid];
    __syncthreads();
    int kmax = tid + 1;
    int k4 = kmax & ~3;
    float s0 = qm, s1 = 0.f, s2 = 0.f, s3 = 0.f;
    int k = 0;
    for (; k < k4; k += 4) {
      s0 = fmaf(qLs[tid][k], eus[k], s0);
      s1 = fmaf(qLs[tid][k + 1], eus[k + 1], s1);
      s2 = fmaf(qLs[tid][k + 2], eus[k + 2], s2);
      s3 = fmaf(qLs[tid][k + 3], eus[k + 3], s3);
    }
    for (; k < kmax; k++) s0 = fmaf(qLs[tid][k], eus[k], s0);
    U[(n * 32 + d) * 128 + tid] = (s0 + s1) + (s2 + s3);
    __syncthreads();
  }
}

// ---------------- A = Kinv @ U ----------------
__global__ __launch_bounds__(256) void k_A2(
    const float* __restrict__ Kinv, const float* __restrict__ U, float* __restrict__ A)
{
  __shared__ float Kis[128][129];
  __shared__ float Us[32][129];
  const int d = blockIdx.x >> 2, nc = blockIdx.x & 3, tid = threadIdx.x;
  const int n0 = nc * 32;
  for (int l = tid; l < 16384; l += 256) Kis[l >> 7][l & 127] = Kinv[d * 16384 + l];
  for (int l = tid; l < 4096; l += 256) Us[l >> 7][l & 127] = U[((n0 + (l >> 7)) * 32 + d) * 128 + (l & 127)];
  __syncthreads();
  for (int e = tid; e < 4096; e += 256) {
    int nl = e >> 7, m = e & 127;
    float s0 = 0.f, s1 = 0.f, s2 = 0.f, s3 = 0.f;
    for (int k = 0; k < 128; k += 4) {
      s0 = fmaf(Kis[m][k], Us[nl][k], s0);
      s1 = fmaf(Kis[m][k + 1], Us[nl][k + 1], s1);
      s2 = fmaf(Kis[m][k + 2], Us[nl][k + 2], s2);
      s3 = fmaf(Kis[m][k + 3], Us[nl][k + 3], s3);
    }
    A[((n0 + nl) * 32 + d) * 128 + m] = (s0 + s1) + (s2 + s3);
  }
}

// ---------------- t = 0: full per-(n,d) GP predict ----------------
__global__ __launch_bounds__(128) void k_t0gp(
    const float* __restrict__ x0, const float* __restrict__ ls, const float* __restrict__ osc,
    const float* __restrict__ qn, const float* __restrict__ zs, const float* __restrict__ zs2,
    const float* __restrict__ Kinv, const float* __restrict__ A,
    const float* __restrict__ ef, const float* __restrict__ eq, float* __restrict__ Xw)
{
  __shared__ float zssT[4096];
  __shared__ float xqs[8][33];
  __shared__ float xq2s[8];
  __shared__ float Kxzs[8][132];
  __shared__ float T1s[8][132];
  __shared__ float covs[8][9];
  __shared__ float Lc[8][9];
  __shared__ float Arow[128];
  const int n = blockIdx.x >> 5, d = blockIdx.x & 31, tid = threadIdx.x;
  const float invl = 1.0f / ls[d], oscd = osc[d];
  for (int l = tid; l < 4096; l += 128) zssT[l] = zs[d*4096 + l];
  for (int l = tid; l < 256; l += 128) {
    int b = l >> 5, k = l & 31;
    xqs[b][k] = x0[((n*32+d)*8 + b)*32 + k] * invl;
  }
  Arow[tid] = A[(n*32+d)*128 + tid];
  __syncthreads();
  if (tid < 8) {
    float s = 0.f;
#pragma unroll
    for (int k = 0; k < 32; k++) { float v = xqs[tid][k]; s = fmaf(v, v, s); }
    xq2s[tid] = s;
  }
  __syncthreads();
  {
    float z2m = zs2[d*128 + tid];
#pragma unroll
    for (int b = 0; b < 8; b++) {
      float dot = 0.f;
#pragma unroll
      for (int k = 0; k < 32; k++) dot = fmaf(xqs[b][k], zssT[k*128 + tid], dot);
      Kxzs[b][tid] = oscd * expf(-0.5f * fmaxf(xq2s[b] + z2m - 2.f*dot, 0.f));
    }
  }
  __syncthreads();
  {
    float a[8] = {0.f,0.f,0.f,0.f,0.f,0.f,0.f,0.f};
    const float* kp = Kinv + d*16384 + tid;
    for (int mm = 0; mm < 128; mm++) {
      float kv = kp[mm*128];
#pragma unroll
      for (int b = 0; b < 8; b++) a[b] = fmaf(Kxzs[b][mm], kv, a[b]);
    }
#pragma unroll
    for (int b = 0; b < 8; b++) T1s[b][tid] = a[b];
  }
  __syncthreads();
  if (tid < 64) {
    int b = tid >> 3, c = tid & 7;
    float dot = 0.f;
#pragma unroll
    for (int k = 0; k < 32; k++) dot = fmaf(xqs[b][k], xqs[c][k], dot);
    float kxx = oscd * expf(-0.5f * fmaxf(xq2s[b] + xq2s[c] - 2.f*dot, 0.f));
    float s0 = 0.f, s1 = 0.f;
    for (int m = 0; m < 128; m += 2) {
      s0 = fmaf(T1s[b][m], Kxzs[c][m], s0);
      s1 = fmaf(T1s[b][m+1], Kxzs[c][m+1], s1);
    }
    covs[b][c] = kxx - (s0+s1) + (b == c ? JITF : 0.f);
  }
  __syncthreads();
  if (tid == 0) {
    for (int a = 0; a < 8; a++) {
      float s = covs[a][a];
      for (int k = 0; k < a; k++) s -= Lc[a][k]*Lc[a][k];
      float la = sqrtf(s);
      Lc[a][a] = la;
      for (int i = a+1; i < 8; i++) {
        float s2 = covs[i][a];
        for (int k = 0; k < a; k++) s2 -= Lc[i][k]*Lc[a][k];
        Lc[i][a] = s2 / la;
      }
      for (int c = a+1; c < 8; c++) Lc[a][c] = 0.f;
    }
  }
  __syncthreads();
  if (tid < 8) {
    int b = tid;
    float m0 = 0.f, m1 = 0.f;
    for (int m = 0; m < 128; m += 2) {
      m0 = fmaf(Kxzs[b][m], Arow[m], m0);
      m1 = fmaf(Kxzs[b][m+1], Arow[m+1], m1);
    }
    float f = m0 + m1;
#pragma unroll
    for (int c = 0; c < 8; c++) f = fmaf(Lc[b][c], ef[(n*32+d)*8 + c], f);
    float X = f + eq[(b*128+n)*32 + d] * sqrtf(qn[d]);
    Xw[(d*8+b)*128 + n] = X;
  }
}

// ---------------- cooperative scan: 32 d-blocks + 8 b-blocks, 1024 thr ----------------
__global__ __launch_bounds__(1024) void k_scan(
    const float* __restrict__ ls, const float* __restrict__ osc,
    const float* __restrict__ qn, const float* __restrict__ rn,
    const float* __restrict__ y,
    const float* __restrict__ ef, const float* __restrict__ eq, const float* __restrict__ er,
    const float* __restrict__ zsg, const float* __restrict__ zs2g,
    const float* __restrict__ Kinvg, const float* __restrict__ Ag,
    float* Xw, float* xm, float* llb, const float* __restrict__ kld,
    float* out, int* cnt)
{
  __shared__ float sm[21952];
  const int blk = blockIdx.x, tid = threadIdx.x;
  int* cntA = cnt;
  int* cntC = cnt + 32;

  if (blk < 32) {
    // ================= d-role =================
    const int d = blk;
    float* AS   = sm;           // [128][132]
    float* KxzS = sm + 16896;   // [8][132]
    float* T1S  = sm + 17952;   // [8][132]
    float* xqS  = sm + 19008;   // [8][36]
    float* xq2S = sm + 19296;   // 8
    float* efS  = sm + 19304;   // [128][9]
    float* eqS  = sm + 20456;   // [8][132]
    float* covS = sm + 21512;   // 81
    float* LcS  = sm + 21593;   // 81
    float* xmS  = sm + 21674;   // 256
    const float invl = 1.0f/ls[d], oscd = osc[d], qsd = sqrtf(qn[d]);
    const float4* KxzS4 = (const float4*)KxzS;
    const float4* T1S4  = (const float4*)T1S;
    const unsigned long long* xm_u = (const unsigned long long*)xm;

    for (int l = tid; l < 16384; l += 1024)
      AS[(l>>7)*132 + (l&127)] = Ag[((l>>7)*32 + d)*128 + (l&127)];
    __syncthreads();

    for (int t = 1; t < 48; t++) {
      // prefetch ef/eq for this (t,d) — hidden behind the wait
      const int pn = tid >> 3, pc = tid & 7;
      const float v_ef = ef[((t*128+pn)*32 + d)*8 + pc];
      const int pb = tid >> 7, pn2 = tid & 127;
      const float v_eq = eq[((t*8+pb)*128 + pn2)*32 + d];

      gwait(cntC, 8*t, tid);
      if (tid < 128) {
        unsigned long long u = aloadu(xm_u + tid);
        float2 f = __builtin_bit_cast(float2, u);
        xmS[2*tid] = f.x; xmS[2*tid+1] = f.y;
      }
      efS[pn*9 + pc] = v_ef;
      eqS[pb*132 + pn2] = v_eq;
      __syncthreads();
      if (tid < 256) { int b = tid>>5, k = tid&31; xqS[b*36+k] = xmS[b*32+k]*invl; }
      __syncthreads();
      if (tid < 8) {
        float s = 0.f;
#pragma unroll
        for (int k = 0; k < 32; k++) { float v = xqS[tid*36+k]; s = fmaf(v,v,s); }
        xq2S[tid] = s;
      }
      __syncthreads();
      { // Kxz: thread (b,m), zs from global (coalesced)
        int b = tid >> 7, m = tid & 127;
        float acc = 0.f;
#pragma unroll
        for (int k = 0; k < 32; k++) acc = fmaf(xqS[b*36+k], zsg[d*4096 + k*128 + m], acc);
        KxzS[b*132+m] = oscd * expf(-0.5f * fmaxf(xq2S[b] + zs2g[d*128+m] - 2.f*acc, 0.f));
      }
      __syncthreads();
      { // T1 = Kxz @ Kinv: thread (b,m), Kinv from global (coalesced, symmetric)
        int b = tid >> 7, m = tid & 127;
        const float* kp = Kinvg + d*16384 + m;
        float a0 = 0.f, a1 = 0.f;
#pragma unroll 8
        for (int mm = 0; mm < 128; mm += 2) {
          a0 = fmaf(KxzS[b*132+mm],   kp[mm*128],       a0);
          a1 = fmaf(KxzS[b*132+mm+1], kp[(mm+1)*128],   a1);
        }
        T1S[b*132+m] = a0 + a1;
      }
      __syncthreads();
      if (tid < 64) { // cov
        int b = tid >> 3, c = tid & 7;
        float4 s4 = {0,0,0,0};
#pragma unroll
        for (int mq = 0; mq < 32; mq++) {
          float4 t1 = T1S4[b*33+mq];
          float4 kx = KxzS4[c*33+mq];
          s4.x = fmaf(t1.x,kx.x,s4.x); s4.y = fmaf(t1.y,kx.y,s4.y);
          s4.z = fmaf(t1.z,kx.z,s4.z); s4.w = fmaf(t1.w,kx.w,s4.w);
        }
        float sc = (s4.x+s4.y)+(s4.z+s4.w);
        float dt = 0.f;
#pragma unroll
        for (int k = 0; k < 32; k++) dt = fmaf(xqS[b*36+k], xqS[c*36+k], dt);
        float kxx = oscd*expf(-0.5f*fmaxf(xq2S[b]+xq2S[c]-2.f*dt, 0.f));
        covS[b*9+c] = kxx - sc + (b==c ? JITF : 0.f);
      }
      __syncthreads();
      if (tid == 0) { // chol 8x8
        for (int a = 0; a < 8; a++) {
          float s = covS[a*9+a];
          for (int k = 0; k < a; k++) s -= LcS[a*9+k]*LcS[a*9+k];
          float la = sqrtf(s);
          LcS[a*9+a] = la;
          for (int i2 = a+1; i2 < 8; i2++) {
            float s2 = covS[i2*9+a];
            for (int k = 0; k < a; k++) s2 -= LcS[i2*9+k]*LcS[a*9+k];
            LcS[i2*9+a] = s2/la;
          }
        }
      }
      __syncthreads();
      { // X = mean + Lc@ef + eq*qsd -> Xw (atomic stores)
        int n = tid >> 3, b = tid & 7;
        float m0 = 0.f, m1 = 0.f;
#pragma unroll 4
        for (int m = 0; m < 128; m += 2) {
          m0 = fmaf(AS[n*132+m],   KxzS[b*132+m],   m0);
          m1 = fmaf(AS[n*132+m+1], KxzS[b*132+m+1], m1);
        }
        float f = m0 + m1;
        for (int c = 0; c <= b; c++) f = fmaf(LcS[b*9+c], efS[n*9+c], f);
        f = fmaf(eqS[b*132+n], qsd, f);
        astoref(Xw + (d*8+b)*128 + n, f);
      }
      gsignal(cntA, tid);
    }
    gwait(cntC, 384, tid);
  } else {
    // ================= b-role =================
    const int b = blk - 32;
    float* XN     = sm;          // [128][33]
    float* redS   = sm + 4224;   // [32][33]
    float* Ps     = sm + 5280;   // [32][36]
    float* Sinv   = sm + 6432;   // [32][33]
    float* Zs     = sm + 7488;   // [32][33]
    float* taperS = sm + 8544;   // 1024
    float* mersS  = sm + 9568;   // [48][32]
    float* rowP   = sm + 11104;  // [2][2][36]
    float* colP   = sm + 11248;  // [2][2][36]
    float* detS   = sm + 11392;  // 16
    float* XmsS   = sm + 11408;  // 32
    float* residS = sm + 11440;  // 32
    float* alphS  = sm + 11472;  // 32
    float* miS    = sm + 11504;  // 32
    float* rsdS   = sm + 11536;  // 32
    float* rnS    = sm + 11568;  // 32
    const float4* er4 = (const float4*)er;
    const unsigned long long* Xw_u = (const unsigned long long*)Xw;

    { // taper
      int l = tid;
      if (l < 1024) {
        int ii = l >> 5, jj = l & 31;
        int ad = ii - jj; if (ad < 0) ad = -ad;
        int dist = (ad < 32 - ad) ? ad : (32 - ad);
        double z = (double)dist / 5.0;
        double z2 = z*z, z3 = z2*z, z4 = z3*z, z5 = z4*z;
        double gval;
        if (z < 1.0) gval = 1.0 - (5.0/3.0)*z2 + (5.0/8.0)*z3 + 0.5*z4 - 0.25*z5;
        else if (z < 2.0) gval = 4.0 - 5.0*z + (5.0/3.0)*z2 + (5.0/8.0)*z3 - 0.5*z4 + (1.0/12.0)*z5 - 2.0/(3.0*z);
        else gval = 0.0;
        taperS[l] = (float)gval;
      }
    }
    if (tid < 32) { rnS[tid] = rn[tid]; rsdS[tid] = sqrtf(rn[tid]); }
    if (tid < 384) { // mers for all t
      int tt = tid >> 3, jq = tid & 7;
      float sx = 0.f, sy = 0.f, sz = 0.f, sw = 0.f;
      for (int n = 0; n < 128; n++) {
        float4 e = er4[((tt*8+b)*128+n)*8 + jq];
        sx += e.x; sy += e.y; sz += e.z; sw += e.w;
      }
      int o = tt*32 + jq*4;
      mersS[o]   = sx*(1.f/128.f);
      mersS[o+1] = sy*(1.f/128.f);
      mersS[o+2] = sz*(1.f/128.f);
      mersS[o+3] = sw*(1.f/128.f);
    }
    __syncthreads();

    float llacc = 0.f;
    const int i = tid >> 5, j = tid & 31;
    for (int t = 0; t < 48; t++) {
      if (t > 0) gwait(cntA, 32*t, tid);
      // load 4 X values (atomic, coherent)
      const int dd = i, q = j;
      unsigned long long u0 = aloadu(Xw_u + (dd*8+b)*64 + q);
      unsigned long long u1 = aloadu(Xw_u + (dd*8+b)*64 + q + 32);
      float2 f0 = __builtin_bit_cast(float2, u0);
      float2 f1 = __builtin_bit_cast(float2, u1);
      redS[dd*33+q] = (f0.x+f0.y)+(f1.x+f1.y);
      __syncthreads();
      if (tid < 32) {
        float s = 0.f;
        for (int c = 0; c < 32; c++) s += redS[tid*33+c];
        XmsS[tid] = s * (1.f/128.f);
      }
      __syncthreads();
      { // centered XN [n][33]
        float mu = XmsS[dd];
        XN[(2*q)*33+dd]    = f0.x - mu;
        XN[(2*q+1)*33+dd]  = f0.y - mu;
        XN[(2*q+64)*33+dd] = f1.x - mu;
        XN[(2*q+65)*33+dd] = f1.y - mu;
      }
      __syncthreads();
      float val;
      { // P[i][j] conflict-free
        float a0 = 0.f, a1 = 0.f;
#pragma unroll 4
        for (int n = 0; n < 128; n += 2) {
          a0 = fmaf(XN[n*33+i],     XN[n*33+j],     a0);
          a1 = fmaf(XN[(n+1)*33+i], XN[(n+1)*33+j], a1);
        }
        float pv = taperS[i*32+j] * (a0+a1) * (1.f/127.f);
        Ps[i*36+j] = pv;
        val = pv + ((i==j) ? rnS[i] : 0.f);
      }
      // 2x2-pivot block sweep of S in registers -> val = (-Sinv)[i][j]
#pragma unroll 1
      for (int kb = 0; kb < 16; kb++) {
        int k0 = kb*2, k1 = k0+1, par = (kb&1)*72;
        if (i == k0) rowP[par + j]      = val;
        if (i == k1) rowP[par + 36 + j] = val;
        if (j == k0) colP[par + i]      = val;
        if (j == k1) colP[par + 36 + i] = val;
        __syncthreads();
        float a  = rowP[par + k0];
        float bb = rowP[par + k1];
        float c  = rowP[par + 36 + k1];
        float det = fmaf(a, c, -bb*bb);
        float idet = 1.0f/det;
        float ci0 = colP[par + i], ci1 = colP[par + 36 + i];
        float r0j = rowP[par + j], r1j = rowP[par + 36 + j];
        float w0 = (ci0*c - ci1*bb)*idet;
        float w1 = (ci1*a - ci0*bb)*idet;
        float v0 = (c*r0j - bb*r1j)*idet;
        float v1 = (a*r1j - bb*r0j)*idet;
        float nv = val - w0*r0j - w1*r1j;
        if (i == k0) nv = v0;
        if (i == k1) nv = v1;
        if (j == k0) nv = w0;
        if (j == k1) nv = w1;
        if (i == k0 && j == k0) nv = -c*idet;
        if (i == k0 && j == k1) nv =  bb*idet;
        if (i == k1 && j == k0) nv =  bb*idet;
        if (i == k1 && j == k1) nv = -a*idet;
        val = nv;
        if (tid == 0) detS[kb] = det;
      }
      Sinv[i*33+j] = -val;
      if (tid < 32) {
        float rs = y[(b*48+t)*32+tid] - XmsS[tid];
        residS[tid] = rs;
        miS[tid] = fmaf(mersS[t*32+tid], rsdS[tid], rs);
      }
      __syncthreads();
      { // Z = Sinv @ P, conflict-free
        float acc = 0.f;
#pragma unroll
        for (int k = 0; k < 32; k++) acc = fmaf(Sinv[i*33+k], Ps[k*36+j], acc);
        Zs[i*33+j] = acc;
      }
      __syncthreads();
      if (tid < 32) { // alpha = Sinv @ resid
        float s = 0.f;
#pragma unroll
        for (int k = 0; k < 32; k++) s = fmaf(Sinv[tid*33+k], residS[k], s);
        alphS[tid] = s;
      } else if (tid >= 64 && tid < 96) { // posterior mean/var
        int ii = tid - 64;
        float xs = 0.f, fv = 0.f;
#pragma unroll
        for (int jj = 0; jj < 32; jj++) {
          float z = Zs[jj*33+ii];
          xs = fmaf(z, miS[jj], xs);
          fv = fmaf(z, Ps[jj*36+ii], fv);
        }
        float xmp = XmsS[ii] + xs;
        out[OFM + (b*48+t)*32 + ii] = xmp;
        out[OFV + (b*48+t)*32 + ii] = Ps[ii*36+ii] - fv;
        astoref(xm + b*32 + ii, xmp);
      }
      gsignal(cntC, tid);
      if (tid == 0) { // ll off the critical path (others blocked at next gwait)
        float quad = 0.f, ld = 0.f;
        for (int k = 0; k < 32; k++) quad = fmaf(residS[k], alphS[k], quad);
        for (int s = 0; s < 16; s++) ld += logf(detS[s]);
        llacc += -0.5f*(32.f*LOG2PIF + ld + quad);
        if (t == 47) astoref(llb + b, llacc);
      }
    }
    gwait(cntC, 384, tid);
  }

  // ---------------- epilogue: x_final broadcast + elbo ----------------
  if (tid < 128) {
    unsigned long long u = aloadu((const unsigned long long*)xm + tid);
    float2 f = __builtin_bit_cast(float2, u);
    sm[2*tid] = f.x; sm[2*tid+1] = f.y;
  }
  __syncthreads();
  for (int v = blk*1024 + tid; v < 1048576; v += 40960)
    out[1 + v] = sm[v & 255];
  if (blk == 32 && tid == 0) {
    double ll = 0.0;
    for (int i2 = 0; i2 < 8; i2++) ll += (double)aloadf(llb + i2);
    double ldK = 0.0, tr = 0.0, mah = 0.0, ldS = 0.0;
    for (int d2 = 0; d2 < 32; d2++) {
      ldK += (double)kld[d2];
      tr  += (double)kld[32+d2];
      mah += (double)kld[64+d2];
      ldS += (double)kld[96+d2];
    }
    double klv = 0.5*(tr + mah - 4096.0 + 2.0*ldK - 2.0*ldS);
    out[0] = (float)(ll - klv/100000.0);
  }
}

extern "C" void kernel_launch(void* const* d_in, const int* in_sizes, int n_in,
                              void* d_out, int out_size, void* d_ws, size_t ws_size,
                              hipStream_t stream) {
  const float* ips = (const float*)d_in[0];
  const float* ls  = (const float*)d_in[2];
  const float* osc = (const float*)d_in[3];
  const float* qmu = (const float*)d_in[4];
  const float* qL  = (const float*)d_in[5];
  const float* qn  = (const float*)d_in[6];
  const float* rn  = (const float*)d_in[7];
  const float* x0  = (const float*)d_in[8];
  const float* y   = (const float*)d_in[9];
  const float* eu  = (const float*)d_in[10];
  const float* ef  = (const float*)d_in[11];
  const float* eq  = (const float*)d_in[12];
  const float* er  = (const float*)d_in[13];
  float* out = (float*)d_out;
  float* ws  = (float*)d_ws;

  float* w_zs   = ws + WZS;
  float* w_zs2  = ws + WZS2;
  float* w_kinv = ws + WKINV;
  float* w_A    = ws + WA;
  float* w_U    = ws + WU;
  float* w_Xw   = ws + WXW;
  float* w_xm   = ws + WXM;
  float* w_llb  = ws + WLLB;
  float* w_kld  = ws + WKLD;
  int*   w_cnt  = (int*)(ws + WCNT);

  k_sweep<<<32, 512, 0, stream>>>(ips, ls, osc, qL, qmu, w_zs, w_zs2, w_kinv, w_kld, w_cnt);
  k_U<<<128, 128, 0, stream>>>(qL, qmu, eu, w_U);
  k_A2<<<128, 256, 0, stream>>>(w_kinv, w_U, w_A);
  k_t0gp<<<4096, 128, 0, stream>>>(x0, ls, osc, qn, w_zs, w_zs2, w_kinv, w_A, ef, eq, w_Xw);
  void* args[] = { (void*)&ls, (void*)&osc, (void*)&qn, (void*)&rn, (void*)&y,
                   (void*)&ef, (void*)&eq, (void*)&er, (void*)&w_zs, (void*)&w_zs2,
                   (void*)&w_kinv, (void*)&w_A, (void*)&w_Xw, (void*)&w_xm, (void*)&w_llb,
                   (void*)&w_kld, (void*)&out, (void*)&w_cnt };
  hipLaunchCooperativeKernel((void*)k_scan, dim3(40), dim3(1024), args, 0, stream);
}

// Round 5
// 2339.402 us; speedup vs baseline: 1.8826x; 1.0059x over previous
//
#include <hip/hip_runtime.h>

#define JITF 1e-4f
#define LOG2PIF 1.8378770664093454f

// sizes: D=32, dy=32, M=128, N=128, B=8, T=48
// ws offsets (floats)
#define WZSM   0          // 32*4096   zs m-major: [d][m][k] (k=0..31)
#define WZS2   131072     // 32*128
#define WKINV  135168     // 32*16384  Kinv[d][i*128+j] (symmetric)
#define WA     659456     // 32*16384  A[(n*32+d)*128+m]
#define WU     1183744    // 128*32*128 U[(n*32+d)*128+m]
#define WXW    1708032    // 32*8*128  Xw[(d*8+b)*128+n]
#define WXM    1740800    // 8*32
#define WLLB   1741056    // 8
#define WKLD   1741088    // 128
#define WCNT   1741248    // int counters: cntA at +0, cntC at +32
// out offsets
#define OFM 1048577
#define OFV 1060865

__device__ __forceinline__ float dot4f(const float4 a, const float4 b) {
  return fmaf(a.x, b.x, fmaf(a.y, b.y, fmaf(a.z, b.z, a.w * b.w)));
}
__device__ __forceinline__ float4 f4_fma(const float4 a, const float s, const float4 c) {
  return make_float4(fmaf(a.x,s,c.x), fmaf(a.y,s,c.y), fmaf(a.z,s,c.z), fmaf(a.w,s,c.w));
}
__device__ __forceinline__ float4 f4_axpby(const float a, const float4 x, const float b, const float4 y) {
  return make_float4(fmaf(a,x.x,b*y.x), fmaf(a,x.y,b*y.y), fmaf(a,x.z,b*y.z), fmaf(a,x.w,b*y.w));
}
__device__ __forceinline__ float aloadf(const float* p) {
  return __hip_atomic_load((float*)p, __ATOMIC_RELAXED, __HIP_MEMORY_SCOPE_AGENT);
}
__device__ __forceinline__ void astoref(float* p, float v) {
  __hip_atomic_store(p, v, __ATOMIC_RELAXED, __HIP_MEMORY_SCOPE_AGENT);
}
__device__ __forceinline__ unsigned long long aloadu(const unsigned long long* p) {
  return __hip_atomic_load((unsigned long long*)p, __ATOMIC_RELAXED, __HIP_MEMORY_SCOPE_AGENT);
}
__device__ __forceinline__ void gwait(int* p, int target, int tid) {
  if (tid == 0) {
    while (__hip_atomic_load(p, __ATOMIC_RELAXED, __HIP_MEMORY_SCOPE_AGENT) < target)
      __builtin_amdgcn_s_sleep(2);
    (void)__hip_atomic_load(p, __ATOMIC_ACQUIRE, __HIP_MEMORY_SCOPE_AGENT);
  }
  __syncthreads();
}
__device__ __forceinline__ void gsignal(int* p, int tid) {
  __syncthreads();
  if (tid == 0) __hip_atomic_fetch_add(p, 1, __ATOMIC_RELEASE, __HIP_MEMORY_SCOPE_AGENT);
}

// ---------------- Kzz build + 2-pivot in-place sweep inverse + KL partials ----------------
__global__ __launch_bounds__(512) void k_sweep(
    const float* __restrict__ ips, const float* __restrict__ ls, const float* __restrict__ osc,
    const float* __restrict__ qL, const float* __restrict__ qmu,
    float* __restrict__ zsMg, float* __restrict__ zs2g,
    float* __restrict__ Kinvg, float* __restrict__ kld, int* cnt)
{
  __shared__ float sm[22792];
  float* cur   = sm;            // [128][132]
  float* zsM   = sm + 16896;    // [128][36]
  float* rowP0 = sm + 21504;    // 132
  float* rowP1 = sm + 21636;    // 132
  float* colP0 = sm + 21768;    // 128
  float* colP1 = sm + 21896;    // 128
  float* qms   = sm + 22024;    // 128
  float* zs2   = sm + 22152;    // 128
  float* red   = sm + 22280;    // 512
  float4* cur4 = (float4*)cur;
  const float4* zsM4 = (const float4*)zsM;
  float4* rowP04 = (float4*)rowP0;
  float4* rowP14 = (float4*)rowP1;
  const int d = blockIdx.x, tid = threadIdx.x;
  const float invl = 1.0f / ls[d], oscd = osc[d];

  if (blockIdx.x == 0 && threadIdx.x == 0) { cnt[0] = 0; cnt[32] = 0; }

  for (int l = tid; l < 4096; l += 512) {
    int m = l >> 5, k = l & 31;
    zsM[m*36+k] = ips[(d*128+m)*32+k] * invl;
  }
  if (tid < 128) qms[tid] = qmu[d*128+tid];
  __syncthreads();
  if (tid < 128) {
    float s = 0.f;
#pragma unroll
    for (int kq = 0; kq < 8; kq++) { float4 v = zsM4[tid*9+kq]; s += dot4f(v, v); }
    zs2[tid] = s; zs2g[d*128+tid] = s;
  }
  for (int l = tid; l < 4096; l += 512) zsMg[d*4096+l] = zsM[(l>>5)*36 + (l&31)];
  __syncthreads();

  const int i = tid >> 2, q = tid & 3;
  { // Kzz build: thread = (row i, col-chunk q)
    float4 zr[8];
#pragma unroll
    for (int kq = 0; kq < 8; kq++) zr[kq] = zsM4[i*9+kq];
    float z2i = zs2[i];
    for (int jj = 0; jj < 32; jj++) {
      int j = q*32 + jj;
      float dot = 0.f;
#pragma unroll
      for (int kq = 0; kq < 8; kq++) dot += dot4f(zr[kq], zsM4[j*9+kq]);
      float d2 = fmaxf(z2i + zs2[j] - 2.f*dot, 0.f);
      cur[i*132+j] = oscd * expf(-0.5f*d2) + (i == j ? JITF : 0.f);
    }
  }
  __syncthreads();

  // 64 2-pivot in-place block-sweep steps -> cur = -Kzz^-1
  float llog = 0.f;
#pragma unroll 1
  for (int kb = 0; kb < 64; kb++) {
    const int k0 = 2*kb, k1 = k0+1;
    if (tid < 33) rowP04[tid] = cur4[k0*33 + tid];
    else if (tid < 66) rowP14[tid-33] = cur4[k1*33 + (tid-33)];
    else if (tid < 194) colP0[tid-66] = cur[(tid-66)*132 + k0];
    else if (tid < 322) colP1[tid-194] = cur[(tid-194)*132 + k1];
    __syncthreads();
    const float a  = rowP0[k0];
    const float bb = rowP0[k1];
    const float c  = rowP1[k1];
    const float det = fmaf(a, c, -bb*bb);
    const float idet = 1.0f/det;
    if (tid == 0) llog += logf(det);
    const float ci0 = colP0[i], ci1 = colP1[i];
    const float w0 = (ci0*c - ci1*bb)*idet;
    const float w1 = (ci1*a - ci0*bb)*idet;
    const bool isk0 = (i == k0), isk1 = (i == k1);
    const int jqp = k0 >> 2;   // f4 index containing both pivot cols
    const int c0 = k0 & 3;     // 0 or 2
#pragma unroll
    for (int jj = 0; jj < 8; jj++) {
      int jq = q*8 + jj;
      float4 r0 = rowP04[jq];
      float4 r1 = rowP14[jq];
      float4 nv;
      if (isk0)      nv = f4_axpby(c*idet, r0, -bb*idet, r1);
      else if (isk1) nv = f4_axpby(-bb*idet, r0, a*idet, r1);
      else {
        nv = cur4[i*33+jq];
        nv = f4_fma(r0, -w0, nv);
        nv = f4_fma(r1, -w1, nv);
      }
      if (jq == jqp) {
        float pv0, pv1;
        if (isk0)      { pv0 = -c*idet;  pv1 =  bb*idet; }
        else if (isk1) { pv0 =  bb*idet; pv1 = -a*idet;  }
        else           { pv0 =  w0;      pv1 =  w1;      }
        if (c0 == 0) { nv.x = pv0; nv.y = pv1; }
        else         { nv.z = pv0; nv.w = pv1; }
      }
      cur4[i*33+jq] = nv;
    }
    __syncthreads();
  }
  // negate -> Kinv
  for (int e = tid; e < 16384; e += 512) { int ii = e>>7, jj = e&127; cur[ii*132+jj] = -cur[ii*132+jj]; }
  __syncthreads();
  for (int l = tid; l < 4096; l += 512) ((float4*)(Kinvg + d*16384))[l] = cur4[(l>>5)*33 + (l&31)];

  if (tid == 0) kld[d] = 0.5f * llog;
  // ldS
  red[tid] = (tid < 128) ? logf(fabsf(qL[(d*128+tid)*128+tid])) : 0.f;
  __syncthreads();
  for (int s = 256; s > 0; s >>= 1) { if (tid < s) red[tid] += red[tid+s]; __syncthreads(); }
  if (tid == 0) kld[96+d] = red[0];
  __syncthreads();
  { // mah = qmu^T Kinv qmu
    float macc = 0.f;
    for (int e = tid; e < 16384; e += 512) {
      int ii = e >> 7, jj = e & 127;
      macc = fmaf(cur[ii*132+jj], qms[ii]*qms[jj], macc);
    }
    red[tid] = macc;
    __syncthreads();
    for (int s = 256; s > 0; s >>= 1) { if (tid < s) red[tid] += red[tid+s]; __syncthreads(); }
    if (tid == 0) kld[64+d] = red[0];
    __syncthreads();
  }
  { // trace = sum_{i,k} qL[i][k] * (Kinv qL)[i][k], qL from global
    float tacc = 0.f;
    for (int e = tid; e < 16384; e += 512) {
      int ii = e >> 7, k2 = e & 127;
      if (k2 <= ii) {
        float w = 0.f;
        for (int m = k2; m < 128; m++) w = fmaf(cur[ii*132+m], qL[(d*128+m)*128+k2], w);
        tacc = fmaf(w, qL[(d*128+ii)*128+k2], tacc);
      }
    }
    red[tid] = tacc;
    __syncthreads();
    for (int s = 256; s > 0; s >>= 1) { if (tid < s) red[tid] += red[tid+s]; __syncthreads(); }
    if (tid == 0) kld[32+d] = red[0];
  }
}

// ---------------- U = q_mu + q_L @ eps_u ----------------
__global__ __launch_bounds__(128) void k_U(
    const float* __restrict__ qL, const float* __restrict__ qmu, const float* __restrict__ eu,
    float* __restrict__ U)
{
  __shared__ float qLs[128][129];
  __shared__ float eus[128];
  const int d = blockIdx.x >> 2, nc = blockIdx.x & 3, tid = threadIdx.x;
  for (int l = tid; l < 16384; l += 128) qLs[l >> 7][l & 127] = qL[d * 16384 + l];
  __syncthreads();
  const float qm = qmu[d * 128 + tid];
  for (int nn = 0; nn < 32; nn++) {
    int n = nc * 32 + nn;
    eus[tid] = eu[(n * 32 + d) * 128 + tid];
    __syncthreads();
    int kmax = tid + 1;
    int k4 = kmax & ~3;
    float s0 = qm, s1 = 0.f, s2 = 0.f, s3 = 0.f;
    int k = 0;
    for (; k < k4; k += 4) {
      s0 = fmaf(qLs[tid][k], eus[k], s0);
      s1 = fmaf(qLs[tid][k + 1], eus[k + 1], s1);
      s2 = fmaf(qLs[tid][k + 2], eus[k + 2], s2);
      s3 = fmaf(qLs[tid][k + 3], eus[k + 3], s3);
    }
    for (; k < kmax; k++) s0 = fmaf(qLs[tid][k], eus[k], s0);
    U[(n * 32 + d) * 128 + tid] = (s0 + s1) + (s2 + s3);
    __syncthreads();
  }
}

// ---------------- A = Kinv @ U ----------------
__global__ __launch_bounds__(256) void k_A2(
    const float* __restrict__ Kinv, const float* __restrict__ U, float* __restrict__ A)
{
  __shared__ float Kis[128][129];
  __shared__ float Us[32][129];
  const int d = blockIdx.x >> 2, nc = blockIdx.x & 3, tid = threadIdx.x;
  const int n0 = nc * 32;
  for (int l = tid; l < 16384; l += 256) Kis[l >> 7][l & 127] = Kinv[d * 16384 + l];
  for (int l = tid; l < 4096; l += 256) Us[l >> 7][l & 127] = U[((n0 + (l >> 7)) * 32 + d) * 128 + (l & 127)];
  __syncthreads();
  for (int e = tid; e < 4096; e += 256) {
    int nl = e >> 7, m = e & 127;
    float s0 = 0.f, s1 = 0.f, s2 = 0.f, s3 = 0.f;
    for (int k = 0; k < 128; k += 4) {
      s0 = fmaf(Kis[m][k], Us[nl][k], s0);
      s1 = fmaf(Kis[m][k + 1], Us[nl][k + 1], s1);
      s2 = fmaf(Kis[m][k + 2], Us[nl][k + 2], s2);
      s3 = fmaf(Kis[m][k + 3], Us[nl][k + 3], s3);
    }
    A[((n0 + nl) * 32 + d) * 128 + m] = (s0 + s1) + (s2 + s3);
  }
}

// ---------------- t = 0: full per-(n,d) GP predict ----------------
__global__ __launch_bounds__(128) void k_t0gp(
    const float* __restrict__ x0, const float* __restrict__ ls, const float* __restrict__ osc,
    const float* __restrict__ qn, const float* __restrict__ zsMg, const float* __restrict__ zs2g,
    const float* __restrict__ Kinv, const float* __restrict__ A,
    const float* __restrict__ ef, const float* __restrict__ eq, float* __restrict__ Xw)
{
  __shared__ float xqs[8*36];
  __shared__ float xq2s[8];
  __shared__ float Kxzs[8*132];
  __shared__ float T1s[8*132];
  __shared__ float covs[8][9];
  __shared__ float Lc[8][9];
  __shared__ float Arow[132];
  const float4* xqs4  = (const float4*)xqs;
  const float4* Kxzs4 = (const float4*)Kxzs;
  const float4* T1s4  = (const float4*)T1s;
  const float4* Arow4 = (const float4*)Arow;
  const int n = blockIdx.x >> 5, d = blockIdx.x & 31, tid = threadIdx.x;
  const float invl = 1.0f / ls[d], oscd = osc[d];

  float4 zr[8];
  {
    const float4* zrow = (const float4*)(zsMg + d*4096 + tid*32);
#pragma unroll
    for (int kq = 0; kq < 8; kq++) zr[kq] = zrow[kq];
  }
  const float z2m = zs2g[d*128 + tid];
  for (int l = tid; l < 256; l += 128) {
    int b = l >> 5, k = l & 31;
    xqs[b*36+k] = x0[((n*32+d)*8 + b)*32 + k] * invl;
  }
  Arow[tid] = A[(n*32+d)*128 + tid];
  __syncthreads();
  if (tid < 8) {
    float s = 0.f;
#pragma unroll
    for (int kq = 0; kq < 8; kq++) { float4 v = xqs4[tid*9+kq]; s += dot4f(v, v); }
    xq2s[tid] = s;
  }
  __syncthreads();
  { // Kxz[b][m], m = tid
#pragma unroll
    for (int b = 0; b < 8; b++) {
      float dot = 0.f;
#pragma unroll
      for (int kq = 0; kq < 8; kq++) dot += dot4f(zr[kq], xqs4[b*9+kq]);
      Kxzs[b*132+tid] = oscd * expf(-0.5f * fmaxf(xq2s[b] + z2m - 2.f*dot, 0.f));
    }
  }
  __syncthreads();
  { // T1[b][m] = sum_mm Kxz[b][mm] * Kinv[mm][m]
    float a[8] = {0.f,0.f,0.f,0.f,0.f,0.f,0.f,0.f};
    const float* kp = Kinv + d*16384 + tid;
    for (int mq = 0; mq < 32; mq++) {
      float kv0 = kp[(4*mq+0)*128];
      float kv1 = kp[(4*mq+1)*128];
      float kv2 = kp[(4*mq+2)*128];
      float kv3 = kp[(4*mq+3)*128];
#pragma unroll
      for (int b = 0; b < 8; b++) {
        float4 kx = Kxzs4[b*33+mq];
        a[b] = fmaf(kx.x, kv0, fmaf(kx.y, kv1, fmaf(kx.z, kv2, fmaf(kx.w, kv3, a[b]))));
      }
    }
#pragma unroll
    for (int b = 0; b < 8; b++) T1s[b*132+tid] = a[b];
  }
  __syncthreads();
  if (tid < 64) {
    int b = tid >> 3, c = tid & 7;
    float sc = 0.f, dt = 0.f;
#pragma unroll
    for (int mq = 0; mq < 32; mq++) sc += dot4f(T1s4[b*33+mq], Kxzs4[c*33+mq]);
#pragma unroll
    for (int kq = 0; kq < 8; kq++) dt += dot4f(xqs4[b*9+kq], xqs4[c*9+kq]);
    float kxx = oscd * expf(-0.5f * fmaxf(xq2s[b] + xq2s[c] - 2.f*dt, 0.f));
    covs[b][c] = kxx - sc + (b == c ? JITF : 0.f);
  }
  __syncthreads();
  if (tid == 0) {
    for (int a = 0; a < 8; a++) {
      float s = covs[a][a];
      for (int k = 0; k < a; k++) s -= Lc[a][k]*Lc[a][k];
      float la = sqrtf(s);
      Lc[a][a] = la;
      for (int i2 = a+1; i2 < 8; i2++) {
        float s2 = covs[i2][a];
        for (int k = 0; k < a; k++) s2 -= Lc[i2][k]*Lc[a][k];
        Lc[i2][a] = s2 / la;
      }
    }
  }
  __syncthreads();
  if (tid < 8) {
    int b = tid;
    float mv = 0.f;
#pragma unroll
    for (int mq = 0; mq < 32; mq++) mv += dot4f(Kxzs4[b*33+mq], Arow4[mq]);
    float f = mv;
#pragma unroll
    for (int c = 0; c < 8; c++) if (c <= b) f = fmaf(Lc[b][c], ef[(n*32+d)*8 + c], f);
    float X = f + eq[(b*128+n)*32 + d] * sqrtf(qn[d]);
    Xw[(d*8+b)*128 + n] = X;
  }
}

// ---------------- cooperative scan: 32 d-blocks + 8 b-blocks, 1024 thr ----------------
__global__ __launch_bounds__(1024) void k_scan(
    const float* __restrict__ ls, const float* __restrict__ osc,
    const float* __restrict__ qn, const float* __restrict__ rn,
    const float* __restrict__ y,
    const float* __restrict__ ef, const float* __restrict__ eq, const float* __restrict__ er,
    const float* __restrict__ zsMg, const float* __restrict__ zs2g,
    const float* __restrict__ Kinvg, const float* __restrict__ Ag,
    float* Xw, float* xm, float* llb, const float* __restrict__ kld,
    float* out, int* cnt)
{
  __shared__ float sm[22016];
  const int blk = blockIdx.x, tid = threadIdx.x;
  int* cntA = cnt;
  int* cntC = cnt + 32;

  if (blk < 32) {
    // ================= d-role =================
    const int d = blk;
    float* AS   = sm;           // [128][132]
    float* KxzS = sm + 16896;   // [8][132]
    float* T1S  = sm + 17952;   // [8][132]
    float* xqS  = sm + 19008;   // [8][36]
    float* efS  = sm + 19296;   // [128][9]
    float* eqS  = sm + 20448;   // [8][132]
    float* covS = sm + 21504;   // 81
    float* LcS  = sm + 21588;   // 81
    float* xmS  = sm + 21672;   // 256
    const float invl = 1.0f/ls[d], oscd = osc[d], qsd = sqrtf(qn[d]);
    const float4* AS4   = (const float4*)AS;
    const float4* KxzS4 = (const float4*)KxzS;
    const float4* T1S4  = (const float4*)T1S;
    const float4* xqS4  = (const float4*)xqS;
    const float4* Kg4   = (const float4*)(Kinvg + d*16384);
    const unsigned long long* xm_u = (const unsigned long long*)xm;

    for (int l = tid; l < 16384; l += 1024)
      AS[(l>>7)*132 + (l&127)] = Ag[((l>>7)*32 + d)*128 + (l&127)];

    // t-invariant per-thread zs row (m = tid&127) + z2
    const int km = tid & 127, kb_ = tid >> 7;
    float4 zr[8];
    {
      const float4* zrow = (const float4*)(zsMg + d*4096 + km*32);
#pragma unroll
      for (int kq = 0; kq < 8; kq++) zr[kq] = zrow[kq];
    }
    const float z2m = zs2g[d*128 + km];
    __syncthreads();

    for (int t = 1; t < 48; t++) {
      // prefetch ef/eq for this (t, d) — hidden behind the wait
      const int pn = tid >> 3, pc = tid & 7;
      const float v_ef = ef[((t*128+pn)*32 + d)*8 + pc];
      const float v_eq = eq[((t*8+kb_)*128 + km)*32 + d];

      gwait(cntC, 8*t, tid);
      if (tid < 128) {
        unsigned long long u = aloadu(xm_u + tid);
        float2 f = __builtin_bit_cast(float2, u);
        xmS[2*tid] = f.x; xmS[2*tid+1] = f.y;
      }
      efS[pn*9 + pc] = v_ef;
      eqS[kb_*132 + km] = v_eq;
      __syncthreads();
      if (tid < 256) { int b = tid>>5, k = tid&31; xqS[b*36+k] = xmS[b*32+k]*invl; }
      __syncthreads();
      { // Kxz[b][m]: b = kb_, m = km (zr in registers, xq broadcast)
        float dot = 0.f, sq = 0.f;
#pragma unroll
        for (int kq = 0; kq < 8; kq++) {
          float4 x4 = xqS4[kb_*9+kq];
          dot += dot4f(zr[kq], x4);
          sq  += dot4f(x4, x4);
        }
        KxzS[kb_*132+km] = oscd * expf(-0.5f * fmaxf(sq + z2m - 2.f*dot, 0.f));
      }
      __syncthreads();
      float mv0 = 0.f, mv1 = 0.f;
      int mn = 0, mb = 0;
      if (tid < 256) {
        // T1[b][4mq..4mq+3] = sum_mm Kxz[b][mm] * Kinv[mm][.]  (4 waves)
        int b = tid >> 5, mq = tid & 31;
        float4 acc = {0.f,0.f,0.f,0.f};
        for (int mm = 0; mm < 128; mm++) {
          float kx = KxzS[b*132+mm];
          acc = f4_fma(Kg4[mm*32+mq], kx, acc);
        }
        ((float4*)T1S)[b*33+mq] = acc;
      } else if (tid >= 512) {
        // mean GEMM (8 waves): thread -> (n, b) and (n, b+4)
        int t2 = tid - 512;
        mn = t2 >> 2; mb = t2 & 3;
#pragma unroll 8
        for (int mq = 0; mq < 32; mq++) {
          float4 a4 = AS4[mn*33+mq];
          mv0 += dot4f(a4, KxzS4[mb*33+mq]);
          mv1 += dot4f(a4, KxzS4[(mb+4)*33+mq]);
        }
      }
      __syncthreads();
      if (tid < 64) { // cov
        int b = tid >> 3, c = tid & 7;
        float sc = 0.f, dt = 0.f, sqb = 0.f, sqc = 0.f;
#pragma unroll
        for (int mq = 0; mq < 32; mq++) sc += dot4f(T1S4[b*33+mq], KxzS4[c*33+mq]);
#pragma unroll
        for (int kq = 0; kq < 8; kq++) {
          float4 xb = xqS4[b*9+kq], xc = xqS4[c*9+kq];
          dt += dot4f(xb, xc); sqb += dot4f(xb, xb); sqc += dot4f(xc, xc);
        }
        float kxx = oscd*expf(-0.5f*fmaxf(sqb + sqc - 2.f*dt, 0.f));
        covS[b*9+c] = kxx - sc + (b==c ? JITF : 0.f);
      }
      __syncthreads();
      if (tid == 0) { // chol 8x8
        for (int a = 0; a < 8; a++) {
          float s = covS[a*9+a];
          for (int k = 0; k < a; k++) s -= LcS[a*9+k]*LcS[a*9+k];
          float la = sqrtf(s);
          LcS[a*9+a] = la;
          for (int i2 = a+1; i2 < 8; i2++) {
            float s2 = covS[i2*9+a];
            for (int k = 0; k < a; k++) s2 -= LcS[i2*9+k]*LcS[a*9+k];
            LcS[i2*9+a] = s2/la;
          }
        }
      }
      __syncthreads();
      if (tid >= 512) { // X assembly + store (2 outputs per thread)
        float f0 = mv0, f1 = mv1;
#pragma unroll
        for (int c = 0; c < 8; c++) {
          float e = efS[mn*9+c];
          if (c <= mb)   f0 = fmaf(LcS[mb*9+c], e, f0);
          if (c <= mb+4) f1 = fmaf(LcS[(mb+4)*9+c], e, f1);
        }
        f0 = fmaf(eqS[mb*132+mn], qsd, f0);
        f1 = fmaf(eqS[(mb+4)*132+mn], qsd, f1);
        astoref(Xw + (d*8+mb)*128 + mn, f0);
        astoref(Xw + (d*8+mb+4)*128 + mn, f1);
      }
      gsignal(cntA, tid);
    }
    gwait(cntC, 384, tid);
  } else {
    // ================= b-role =================
    const int b = blk - 32;
    float* XNT    = sm;          // [32][128] swizzled, uncentered
    float* redS   = sm + 4096;   // [32][33]
    float* Ps     = sm + 5152;   // [32][36]
    float* Sinv   = sm + 6304;   // [32][36]
    float* Zs     = sm + 7456;   // [32][33]
    float* taperS = sm + 8512;   // 1024
    float* mersS  = sm + 9536;   // [48][32]
    float* rowP   = sm + 11072;  // [2][2][36]
    float* colP   = sm + 11216;  // [2][2][36]
    float* detS   = sm + 11360;  // 16
    float* XmsS   = sm + 11376;  // 32
    float* residS = sm + 11408;  // 32
    float* alphS  = sm + 11440;  // 32
    float* miS    = sm + 11472;  // 32
    float* rsdS   = sm + 11504;  // 32
    float* rnS    = sm + 11536;  // 32
    const float4* XNT4 = (const float4*)XNT;
    const float4* Ps4  = (const float4*)Ps;
    const float4* Sinv4 = (const float4*)Sinv;
    const float4* er4 = (const float4*)er;
    const unsigned long long* Xw_u = (const unsigned long long*)Xw;

    { // taper
      int l = tid;
      if (l < 1024) {
        int ii = l >> 5, jj = l & 31;
        int ad = ii - jj; if (ad < 0) ad = -ad;
        int dist = (ad < 32 - ad) ? ad : (32 - ad);
        double z = (double)dist / 5.0;
        double z2 = z*z, z3 = z2*z, z4 = z3*z, z5 = z4*z;
        double gval;
        if (z < 1.0) gval = 1.0 - (5.0/3.0)*z2 + (5.0/8.0)*z3 + 0.5*z4 - 0.25*z5;
        else if (z < 2.0) gval = 4.0 - 5.0*z + (5.0/3.0)*z2 + (5.0/8.0)*z3 - 0.5*z4 + (1.0/12.0)*z5 - 2.0/(3.0*z);
        else gval = 0.0;
        taperS[l] = (float)gval;
      }
    }
    if (tid < 32) { rnS[tid] = rn[tid]; rsdS[tid] = sqrtf(rn[tid]); }
    if (tid < 384) { // mers for all t
      int tt = tid >> 3, jq = tid & 7;
      float sx = 0.f, sy = 0.f, sz = 0.f, sw = 0.f;
      for (int n = 0; n < 128; n++) {
        float4 e = er4[((tt*8+b)*128+n)*8 + jq];
        sx += e.x; sy += e.y; sz += e.z; sw += e.w;
      }
      int o = tt*32 + jq*4;
      mersS[o]   = sx*(1.f/128.f);
      mersS[o+1] = sy*(1.f/128.f);
      mersS[o+2] = sz*(1.f/128.f);
      mersS[o+3] = sw*(1.f/128.f);
    }
    __syncthreads();

    float llacc = 0.f;
    const int i = tid >> 5, j = tid & 31;
    for (int t = 0; t < 48; t++) {
      if (t > 0) gwait(cntA, 32*t, tid);
      // load 4 X values; write swizzled XNT (uncentered) + row partial sums
      {
        const int dd = i, q = j;
        unsigned long long u0 = aloadu(Xw_u + (dd*8+b)*64 + q);
        unsigned long long u1 = aloadu(Xw_u + (dd*8+b)*64 + q + 32);
        float2 f0 = __builtin_bit_cast(float2, u0);
        float2 f1 = __builtin_bit_cast(float2, u1);
        redS[dd*33+q] = (f0.x+f0.y)+(f1.x+f1.y);
        // swizzled scalar writes: logical n -> f4-slot (f&24)|((f^dd)&7)
        int f0i = q >> 1;                 // n = 2q
        int s0 = (f0i & 24) | ((f0i ^ dd) & 7);
        int base0 = dd*128 + s0*4 + ((2*q) & 3);
        XNT[base0]     = f0.x;
        XNT[base0 + 1] = f0.y;            // n=2q+1 shares the f4 (2q&3 in {0,2})
        int f1i = (q >> 1) + 16;          // n = 2q+64
        int s1 = (f1i & 24) | ((f1i ^ dd) & 7);
        int base1 = dd*128 + s1*4 + ((2*q) & 3);
        XNT[base1]     = f1.x;
        XNT[base1 + 1] = f1.y;
      }
      __syncthreads();
      if (tid < 32) {
        float s = 0.f;
        for (int c = 0; c < 32; c++) s += redS[tid*33+c];
        XmsS[tid] = s * (1.f/128.f);
      }
      __syncthreads();
      float val;
      { // P[i][j] via uncentered Gram (swizzled conflict-free f4 reads)
        float g = 0.f;
#pragma unroll 8
        for (int nq = 0; nq < 32; nq++) {
          int si = (nq & 24) | ((nq ^ i) & 7);
          int sj = (nq & 24) | ((nq ^ j) & 7);
          g += dot4f(XNT4[i*32+si], XNT4[j*32+sj]);
        }
        float pv = taperS[i*32+j] * (g - 128.f*XmsS[i]*XmsS[j]) * (1.f/127.f);
        Ps[i*36+j] = pv;
        val = pv + ((i==j) ? rnS[i] : 0.f);
      }
      // 2x2-pivot block sweep of S in registers -> val = (-Sinv)[i][j]
#pragma unroll 1
      for (int kb = 0; kb < 16; kb++) {
        int k0 = kb*2, k1 = k0+1, par = (kb&1)*72;
        if (i == k0) rowP[par + j]      = val;
        if (i == k1) rowP[par + 36 + j] = val;
        if (j == k0) colP[par + i]      = val;
        if (j == k1) colP[par + 36 + i] = val;
        __syncthreads();
        float a  = rowP[par + k0];
        float bb = rowP[par + k1];
        float c  = rowP[par + 36 + k1];
        float det = fmaf(a, c, -bb*bb);
        float idet = 1.0f/det;
        float ci0 = colP[par + i], ci1 = colP[par + 36 + i];
        float r0j = rowP[par + j], r1j = rowP[par + 36 + j];
        float w0 = (ci0*c - ci1*bb)*idet;
        float w1 = (ci1*a - ci0*bb)*idet;
        float v0 = (c*r0j - bb*r1j)*idet;
        float v1 = (a*r1j - bb*r0j)*idet;
        float nv = val - w0*r0j - w1*r1j;
        if (i == k0) nv = v0;
        if (i == k1) nv = v1;
        if (j == k0) nv = w0;
        if (j == k1) nv = w1;
        if (i == k0 && j == k0) nv = -c*idet;
        if (i == k0 && j == k1) nv =  bb*idet;
        if (i == k1 && j == k0) nv =  bb*idet;
        if (i == k1 && j == k1) nv = -a*idet;
        val = nv;
        if (tid == 0) detS[kb] = det;
      }
      Sinv[i*36+j] = -val;
      if (tid < 32) {
        float rs = y[(b*48+t)*32+tid] - XmsS[tid];
        residS[tid] = rs;
        miS[tid] = fmaf(mersS[t*32+tid], rsdS[tid], rs);
      }
      __syncthreads();
      { // Z = Sinv @ P (P symmetric -> dual row-reads, f4)
        float zacc = 0.f;
#pragma unroll
        for (int kq = 0; kq < 8; kq++) zacc += dot4f(Sinv4[i*9+kq], Ps4[j*9+kq]);
        Zs[i*33+j] = zacc;
      }
      __syncthreads();
      if (tid < 32) { // alpha = Sinv @ resid
        float s = 0.f;
#pragma unroll
        for (int k = 0; k < 32; k++) s = fmaf(Sinv[tid*36+k], residS[k], s);
        alphS[tid] = s;
      } else if (tid >= 64 && tid < 96) { // posterior mean/var
        int ii = tid - 64;
        float xs = 0.f, fv = 0.f;
#pragma unroll
        for (int jj = 0; jj < 32; jj++) {
          float z = Zs[jj*33+ii];
          xs = fmaf(z, miS[jj], xs);
          fv = fmaf(z, Ps[jj*36+ii], fv);
        }
        float xmp = XmsS[ii] + xs;
        out[OFM + (b*48+t)*32 + ii] = xmp;
        out[OFV + (b*48+t)*32 + ii] = Ps[ii*36+ii] - fv;
        astoref(xm + b*32 + ii, xmp);
      }
      gsignal(cntC, tid);
      if (tid == 0) { // ll off the critical path
        float quad = 0.f, ld = 0.f;
        for (int k = 0; k < 32; k++) quad = fmaf(residS[k], alphS[k], quad);
        for (int s = 0; s < 16; s++) ld += logf(detS[s]);
        llacc += -0.5f*(32.f*LOG2PIF + ld + quad);
        if (t == 47) astoref(llb + b, llacc);
      }
    }
    gwait(cntC, 384, tid);
  }

  // ---------------- epilogue: x_final broadcast + elbo ----------------
  if (tid < 128) {
    unsigned long long u = aloadu((const unsigned long long*)xm + tid);
    float2 f = __builtin_bit_cast(float2, u);
    sm[2*tid] = f.x; sm[2*tid+1] = f.y;
  }
  __syncthreads();
  for (int v = blk*1024 + tid; v < 1048576; v += 40960)
    out[1 + v] = sm[v & 255];
  if (blk == 32 && tid == 0) {
    double ll = 0.0;
    for (int i2 = 0; i2 < 8; i2++) ll += (double)aloadf(llb + i2);
    double ldK = 0.0, tr = 0.0, mah = 0.0, ldS = 0.0;
    for (int d2 = 0; d2 < 32; d2++) {
      ldK += (double)kld[d2];
      tr  += (double)kld[32+d2];
      mah += (double)kld[64+d2];
      ldS += (double)kld[96+d2];
    }
    double klv = 0.5*(tr + mah - 4096.0 + 2.0*ldK - 2.0*ldS);
    out[0] = (float)(ll - klv/100000.0);
  }
}

extern "C" void kernel_launch(void* const* d_in, const int* in_sizes, int n_in,
                              void* d_out, int out_size, void* d_ws, size_t ws_size,
                              hipStream_t stream) {
  const float* ips = (const float*)d_in[0];
  const float* ls  = (const float*)d_in[2];
  const float* osc = (const float*)d_in[3];
  const float* qmu = (const float*)d_in[4];
  const float* qL  = (const float*)d_in[5];
  const float* qn  = (const float*)d_in[6];
  const float* rn  = (const float*)d_in[7];
  const float* x0  = (const float*)d_in[8];
  const float* y   = (const float*)d_in[9];
  const float* eu  = (const float*)d_in[10];
  const float* ef  = (const float*)d_in[11];
  const float* eq  = (const float*)d_in[12];
  const float* er  = (const float*)d_in[13];
  float* out = (float*)d_out;
  float* ws  = (float*)d_ws;

  float* w_zsm  = ws + WZSM;
  float* w_zs2  = ws + WZS2;
  float* w_kinv = ws + WKINV;
  float* w_A    = ws + WA;
  float* w_U    = ws + WU;
  float* w_Xw   = ws + WXW;
  float* w_xm   = ws + WXM;
  float* w_llb  = ws + WLLB;
  float* w_kld  = ws + WKLD;
  int*   w_cnt  = (int*)(ws + WCNT);

  k_sweep<<<32, 512, 0, stream>>>(ips, ls, osc, qL, qmu, w_zsm, w_zs2, w_kinv, w_kld, w_cnt);
  k_U<<<128, 128, 0, stream>>>(qL, qmu, eu, w_U);
  k_A2<<<128, 256, 0, stream>>>(w_kinv, w_U, w_A);
  k_t0gp<<<4096, 128, 0, stream>>>(x0, ls, osc, qn, w_zsm, w_zs2, w_kinv, w_A, ef, eq, w_Xw);
  void* args[] = { (void*)&ls, (void*)&osc, (void*)&qn, (void*)&rn, (void*)&y,
                   (void*)&ef, (void*)&eq, (void*)&er, (void*)&w_zsm, (void*)&w_zs2,
                   (void*)&w_kinv, (void*)&w_A, (void*)&w_Xw, (void*)&w_xm, (void*)&w_llb,
                   (void*)&w_kld, (void*)&out, (void*)&w_cnt };
  hipLaunchCooperativeKernel((void*)k_scan, dim3(40), dim3(1024), args, 0, stream);
}

// Round 6
// 1916.624 us; speedup vs baseline: 2.2979x; 1.2206x over previous
//
#include <hip/hip_runtime.h>

#define JITF 1e-4f
#define LOG2PIF 1.8378770664093454f

// sizes: D=32, dy=32, M=128, N=128, B=8, T=48
// ws offsets (floats)
#define WZSM   0          // 32*4096   zs m-major: [d][m][k] (k=0..31)
#define WZS2   131072     // 32*128
#define WKINV  135168     // 32*16384  Kinv[d][i*128+j] (symmetric)
#define WA     659456     // 32*16384  A[(n*32+d)*128+m]
#define WU     1183744    // 128*32*128 U[(n*32+d)*128+m]
#define WXW    1708032    // 32*8*128  Xw[(d*8+b)*128+n]
#define WXM    1740800    // 8*32
#define WLLB   1741056    // 8
#define WKLD   1741088    // 128
#define WCNT   1741248    // int flags: d-block d at [d*16], b-block b at [(32+b)*16]
// out offsets
#define OFM 1048577
#define OFV 1060865

__device__ __forceinline__ float dot4f(const float4 a, const float4 b) {
  return fmaf(a.x, b.x, fmaf(a.y, b.y, fmaf(a.z, b.z, a.w * b.w)));
}
__device__ __forceinline__ float4 f4_fma(const float4 a, const float s, const float4 c) {
  return make_float4(fmaf(a.x,s,c.x), fmaf(a.y,s,c.y), fmaf(a.z,s,c.z), fmaf(a.w,s,c.w));
}
__device__ __forceinline__ float4 f4_axpby(const float a, const float4 x, const float b, const float4 y) {
  return make_float4(fmaf(a,x.x,b*y.x), fmaf(a,x.y,b*y.y), fmaf(a,x.z,b*y.z), fmaf(a,x.w,b*y.w));
}
__device__ __forceinline__ float aloadf(const float* p) {
  return __hip_atomic_load((float*)p, __ATOMIC_RELAXED, __HIP_MEMORY_SCOPE_AGENT);
}
__device__ __forceinline__ void astoref(float* p, float v) {
  __hip_atomic_store(p, v, __ATOMIC_RELAXED, __HIP_MEMORY_SCOPE_AGENT);
}
__device__ __forceinline__ unsigned long long aloadu(const unsigned long long* p) {
  return __hip_atomic_load((unsigned long long*)p, __ATOMIC_RELAXED, __HIP_MEMORY_SCOPE_AGENT);
}
// relaxed poll on a private flag word (no RMW, no per-poll invalidate)
__device__ __forceinline__ void pollge(const int* p, int target) {
  while (__hip_atomic_load((int*)p, __ATOMIC_RELAXED, __HIP_MEMORY_SCOPE_AGENT) < target)
    __builtin_amdgcn_s_sleep(1);
}
// __syncthreads drains vmcnt; then tid0's release store publishes the step
__device__ __forceinline__ void gsignal(int* p, int val, int tid) {
  __syncthreads();
  if (tid == 0) __hip_atomic_store(p, val, __ATOMIC_RELEASE, __HIP_MEMORY_SCOPE_AGENT);
}

// ---------------- Kzz build + 2-pivot in-place sweep inverse + KL partials ----------------
__global__ __launch_bounds__(512) void k_sweep(
    const float* __restrict__ ips, const float* __restrict__ ls, const float* __restrict__ osc,
    const float* __restrict__ qL, const float* __restrict__ qmu,
    float* __restrict__ zsMg, float* __restrict__ zs2g,
    float* __restrict__ Kinvg, float* __restrict__ kld, int* cnt)
{
  __shared__ float sm[22792];
  float* cur   = sm;            // [128][132]
  float* zsM   = sm + 16896;    // [128][36]
  float* rowP0 = sm + 21504;    // 132
  float* rowP1 = sm + 21636;    // 132
  float* colP0 = sm + 21768;    // 128
  float* colP1 = sm + 21896;    // 128
  float* qms   = sm + 22024;    // 128
  float* zs2   = sm + 22152;    // 128
  float* red   = sm + 22280;    // 512
  float4* cur4 = (float4*)cur;
  const float4* zsM4 = (const float4*)zsM;
  float4* rowP04 = (float4*)rowP0;
  float4* rowP14 = (float4*)rowP1;
  const int d = blockIdx.x, tid = threadIdx.x;
  const float invl = 1.0f / ls[d], oscd = osc[d];

  if (blockIdx.x == 0) { for (int l = tid; l < 640; l += 512) cnt[l] = 0; }

  for (int l = tid; l < 4096; l += 512) {
    int m = l >> 5, k = l & 31;
    zsM[m*36+k] = ips[(d*128+m)*32+k] * invl;
  }
  if (tid < 128) qms[tid] = qmu[d*128+tid];
  __syncthreads();
  if (tid < 128) {
    float s = 0.f;
#pragma unroll
    for (int kq = 0; kq < 8; kq++) { float4 v = zsM4[tid*9+kq]; s += dot4f(v, v); }
    zs2[tid] = s; zs2g[d*128+tid] = s;
  }
  for (int l = tid; l < 4096; l += 512) zsMg[d*4096+l] = zsM[(l>>5)*36 + (l&31)];
  __syncthreads();

  const int i = tid >> 2, q = tid & 3;
  { // Kzz build: thread = (row i, col-chunk q)
    float4 zr[8];
#pragma unroll
    for (int kq = 0; kq < 8; kq++) zr[kq] = zsM4[i*9+kq];
    float z2i = zs2[i];
    for (int jj = 0; jj < 32; jj++) {
      int j = q*32 + jj;
      float dot = 0.f;
#pragma unroll
      for (int kq = 0; kq < 8; kq++) dot += dot4f(zr[kq], zsM4[j*9+kq]);
      float d2 = fmaxf(z2i + zs2[j] - 2.f*dot, 0.f);
      cur[i*132+j] = oscd * expf(-0.5f*d2) + (i == j ? JITF : 0.f);
    }
  }
  __syncthreads();

  // 64 2-pivot in-place block-sweep steps -> cur = -Kzz^-1
  float llog = 0.f;
#pragma unroll 1
  for (int kb = 0; kb < 64; kb++) {
    const int k0 = 2*kb, k1 = k0+1;
    if (tid < 33) rowP04[tid] = cur4[k0*33 + tid];
    else if (tid < 66) rowP14[tid-33] = cur4[k1*33 + (tid-33)];
    else if (tid < 194) colP0[tid-66] = cur[(tid-66)*132 + k0];
    else if (tid < 322) colP1[tid-194] = cur[(tid-194)*132 + k1];
    __syncthreads();
    const float a  = rowP0[k0];
    const float bb = rowP0[k1];
    const float c  = rowP1[k1];
    const float det = fmaf(a, c, -bb*bb);
    const float idet = 1.0f/det;
    if (tid == 0) llog += logf(det);
    const float ci0 = colP0[i], ci1 = colP1[i];
    const float w0 = (ci0*c - ci1*bb)*idet;
    const float w1 = (ci1*a - ci0*bb)*idet;
    const bool isk0 = (i == k0), isk1 = (i == k1);
    const int jqp = k0 >> 2;
    const int c0 = k0 & 3;
#pragma unroll
    for (int jj = 0; jj < 8; jj++) {
      int jq = q*8 + jj;
      float4 r0 = rowP04[jq];
      float4 r1 = rowP14[jq];
      float4 nv;
      if (isk0)      nv = f4_axpby(c*idet, r0, -bb*idet, r1);
      else if (isk1) nv = f4_axpby(-bb*idet, r0, a*idet, r1);
      else {
        nv = cur4[i*33+jq];
        nv = f4_fma(r0, -w0, nv);
        nv = f4_fma(r1, -w1, nv);
      }
      if (jq == jqp) {
        float pv0, pv1;
        if (isk0)      { pv0 = -c*idet;  pv1 =  bb*idet; }
        else if (isk1) { pv0 =  bb*idet; pv1 = -a*idet;  }
        else           { pv0 =  w0;      pv1 =  w1;      }
        if (c0 == 0) { nv.x = pv0; nv.y = pv1; }
        else         { nv.z = pv0; nv.w = pv1; }
      }
      cur4[i*33+jq] = nv;
    }
    __syncthreads();
  }
  for (int e = tid; e < 16384; e += 512) { int ii = e>>7, jj = e&127; cur[ii*132+jj] = -cur[ii*132+jj]; }
  __syncthreads();
  for (int l = tid; l < 4096; l += 512) ((float4*)(Kinvg + d*16384))[l] = cur4[(l>>5)*33 + (l&31)];

  if (tid == 0) kld[d] = 0.5f * llog;
  red[tid] = (tid < 128) ? logf(fabsf(qL[(d*128+tid)*128+tid])) : 0.f;
  __syncthreads();
  for (int s = 256; s > 0; s >>= 1) { if (tid < s) red[tid] += red[tid+s]; __syncthreads(); }
  if (tid == 0) kld[96+d] = red[0];
  __syncthreads();
  {
    float macc = 0.f;
    for (int e = tid; e < 16384; e += 512) {
      int ii = e >> 7, jj = e & 127;
      macc = fmaf(cur[ii*132+jj], qms[ii]*qms[jj], macc);
    }
    red[tid] = macc;
    __syncthreads();
    for (int s = 256; s > 0; s >>= 1) { if (tid < s) red[tid] += red[tid+s]; __syncthreads(); }
    if (tid == 0) kld[64+d] = red[0];
    __syncthreads();
  }
  {
    float tacc = 0.f;
    for (int e = tid; e < 16384; e += 512) {
      int ii = e >> 7, k2 = e & 127;
      if (k2 <= ii) {
        float w = 0.f;
        for (int m = k2; m < 128; m++) w = fmaf(cur[ii*132+m], qL[(d*128+m)*128+k2], w);
        tacc = fmaf(w, qL[(d*128+ii)*128+k2], tacc);
      }
    }
    red[tid] = tacc;
    __syncthreads();
    for (int s = 256; s > 0; s >>= 1) { if (tid < s) red[tid] += red[tid+s]; __syncthreads(); }
    if (tid == 0) kld[32+d] = red[0];
  }
}

// ---------------- U = q_mu + q_L @ eps_u ----------------
__global__ __launch_bounds__(128) void k_U(
    const float* __restrict__ qL, const float* __restrict__ qmu, const float* __restrict__ eu,
    float* __restrict__ U)
{
  __shared__ float qLs[128][129];
  __shared__ float eus[128];
  const int d = blockIdx.x >> 2, nc = blockIdx.x & 3, tid = threadIdx.x;
  for (int l = tid; l < 16384; l += 128) qLs[l >> 7][l & 127] = qL[d * 16384 + l];
  __syncthreads();
  const float qm = qmu[d * 128 + tid];
  for (int nn = 0; nn < 32; nn++) {
    int n = nc * 32 + nn;
    eus[tid] = eu[(n * 32 + d) * 128 + tid];
    __syncthreads();
    int kmax = tid + 1;
    int k4 = kmax & ~3;
    float s0 = qm, s1 = 0.f, s2 = 0.f, s3 = 0.f;
    int k = 0;
    for (; k < k4; k += 4) {
      s0 = fmaf(qLs[tid][k], eus[k], s0);
      s1 = fmaf(qLs[tid][k + 1], eus[k + 1], s1);
      s2 = fmaf(qLs[tid][k + 2], eus[k + 2], s2);
      s3 = fmaf(qLs[tid][k + 3], eus[k + 3], s3);
    }
    for (; k < kmax; k++) s0 = fmaf(qLs[tid][k], eus[k], s0);
    U[(n * 32 + d) * 128 + tid] = (s0 + s1) + (s2 + s3);
    __syncthreads();
  }
}

// ---------------- A = Kinv @ U ----------------
__global__ __launch_bounds__(256) void k_A2(
    const float* __restrict__ Kinv, const float* __restrict__ U, float* __restrict__ A)
{
  __shared__ float Kis[128][129];
  __shared__ float Us[32][129];
  const int d = blockIdx.x >> 2, nc = blockIdx.x & 3, tid = threadIdx.x;
  const int n0 = nc * 32;
  for (int l = tid; l < 16384; l += 256) Kis[l >> 7][l & 127] = Kinv[d * 16384 + l];
  for (int l = tid; l < 4096; l += 256) Us[l >> 7][l & 127] = U[((n0 + (l >> 7)) * 32 + d) * 128 + (l & 127)];
  __syncthreads();
  for (int e = tid; e < 4096; e += 256) {
    int nl = e >> 7, m = e & 127;
    float s0 = 0.f, s1 = 0.f, s2 = 0.f, s3 = 0.f;
    for (int k = 0; k < 128; k += 4) {
      s0 = fmaf(Kis[m][k], Us[nl][k], s0);
      s1 = fmaf(Kis[m][k + 1], Us[nl][k + 1], s1);
      s2 = fmaf(Kis[m][k + 2], Us[nl][k + 2], s2);
      s3 = fmaf(Kis[m][k + 3], Us[nl][k + 3], s3);
    }
    A[((n0 + nl) * 32 + d) * 128 + m] = (s0 + s1) + (s2 + s3);
  }
}

// ---------------- t = 0: full per-(n,d) GP predict ----------------
__global__ __launch_bounds__(128) void k_t0gp(
    const float* __restrict__ x0, const float* __restrict__ ls, const float* __restrict__ osc,
    const float* __restrict__ qn, const float* __restrict__ zsMg, const float* __restrict__ zs2g,
    const float* __restrict__ Kinv, const float* __restrict__ A,
    const float* __restrict__ ef, const float* __restrict__ eq, float* __restrict__ Xw)
{
  __shared__ float xqs[8*36];
  __shared__ float xq2s[8];
  __shared__ float Kxzs[8*132];
  __shared__ float T1s[8*132];
  __shared__ float covs[8][9];
  __shared__ float Lc[8][9];
  __shared__ float Arow[132];
  const float4* xqs4  = (const float4*)xqs;
  const float4* Kxzs4 = (const float4*)Kxzs;
  const float4* T1s4  = (const float4*)T1s;
  const float4* Arow4 = (const float4*)Arow;
  const int n = blockIdx.x >> 5, d = blockIdx.x & 31, tid = threadIdx.x;
  const float invl = 1.0f / ls[d], oscd = osc[d];

  float4 zr[8];
  {
    const float4* zrow = (const float4*)(zsMg + d*4096 + tid*32);
#pragma unroll
    for (int kq = 0; kq < 8; kq++) zr[kq] = zrow[kq];
  }
  const float z2m = zs2g[d*128 + tid];
  for (int l = tid; l < 256; l += 128) {
    int b = l >> 5, k = l & 31;
    xqs[b*36+k] = x0[((n*32+d)*8 + b)*32 + k] * invl;
  }
  Arow[tid] = A[(n*32+d)*128 + tid];
  __syncthreads();
  if (tid < 8) {
    float s = 0.f;
#pragma unroll
    for (int kq = 0; kq < 8; kq++) { float4 v = xqs4[tid*9+kq]; s += dot4f(v, v); }
    xq2s[tid] = s;
  }
  __syncthreads();
  {
#pragma unroll
    for (int b = 0; b < 8; b++) {
      float dot = 0.f;
#pragma unroll
      for (int kq = 0; kq < 8; kq++) dot += dot4f(zr[kq], xqs4[b*9+kq]);
      Kxzs[b*132+tid] = oscd * expf(-0.5f * fmaxf(xq2s[b] + z2m - 2.f*dot, 0.f));
    }
  }
  __syncthreads();
  {
    float a[8] = {0.f,0.f,0.f,0.f,0.f,0.f,0.f,0.f};
    const float* kp = Kinv + d*16384 + tid;
    for (int mq = 0; mq < 32; mq++) {
      float kv0 = kp[(4*mq+0)*128];
      float kv1 = kp[(4*mq+1)*128];
      float kv2 = kp[(4*mq+2)*128];
      float kv3 = kp[(4*mq+3)*128];
#pragma unroll
      for (int b = 0; b < 8; b++) {
        float4 kx = Kxzs4[b*33+mq];
        a[b] = fmaf(kx.x, kv0, fmaf(kx.y, kv1, fmaf(kx.z, kv2, fmaf(kx.w, kv3, a[b]))));
      }
    }
#pragma unroll
    for (int b = 0; b < 8; b++) T1s[b*132+tid] = a[b];
  }
  __syncthreads();
  if (tid < 64) {
    int b = tid >> 3, c = tid & 7;
    float sc = 0.f, dt = 0.f;
#pragma unroll
    for (int mq = 0; mq < 32; mq++) sc += dot4f(T1s4[b*33+mq], Kxzs4[c*33+mq]);
#pragma unroll
    for (int kq = 0; kq < 8; kq++) dt += dot4f(xqs4[b*9+kq], xqs4[c*9+kq]);
    float kxx = oscd * expf(-0.5f * fmaxf(xq2s[b] + xq2s[c] - 2.f*dt, 0.f));
    covs[b][c] = kxx - sc + (b == c ? JITF : 0.f);
  }
  __syncthreads();
  if (tid == 0) {
    for (int a = 0; a < 8; a++) {
      float s = covs[a][a];
      for (int k = 0; k < a; k++) s -= Lc[a][k]*Lc[a][k];
      float la = sqrtf(s);
      Lc[a][a] = la;
      for (int i2 = a+1; i2 < 8; i2++) {
        float s2 = covs[i2][a];
        for (int k = 0; k < a; k++) s2 -= Lc[i2][k]*Lc[a][k];
        Lc[i2][a] = s2 / la;
      }
    }
  }
  __syncthreads();
  if (tid < 8) {
    int b = tid;
    float mv = 0.f;
#pragma unroll
    for (int mq = 0; mq < 32; mq++) mv += dot4f(Kxzs4[b*33+mq], Arow4[mq]);
    float f = mv;
#pragma unroll
    for (int c = 0; c < 8; c++) if (c <= b) f = fmaf(Lc[b][c], ef[(n*32+d)*8 + c], f);
    float X = f + eq[(b*128+n)*32 + d] * sqrtf(qn[d]);
    Xw[(d*8+b)*128 + n] = X;
  }
}

// ---------------- cooperative scan: 32 d-blocks + 8 b-blocks, 1024 thr ----------------
__global__ __launch_bounds__(1024) void k_scan(
    const float* __restrict__ ls, const float* __restrict__ osc,
    const float* __restrict__ qn, const float* __restrict__ rn,
    const float* __restrict__ y,
    const float* __restrict__ ef, const float* __restrict__ eq, const float* __restrict__ er,
    const float* __restrict__ zsMg, const float* __restrict__ zs2g,
    const float* __restrict__ Kinvg, const float* __restrict__ Ag,
    float* Xw, float* xm, float* llb, const float* __restrict__ kld,
    float* out, int* cnt)
{
  __shared__ float sm[36704];
  const int blk = blockIdx.x, tid = threadIdx.x;

  if (blk < 32) {
    // ================= d-role =================
    const int d = blk;
    float* KinvS = sm;           // [128][129] 16512
    float* AT    = sm + 16512;   // [128][129] 16512  (AT[m][n] = A[n][m])
    float* KxzS  = sm + 33024;   // [8][132]   1056
    float* T1S   = sm + 34080;   // [8][132]   1056
    float* xqS   = sm + 35136;   // [8][36]    288
    float* efS   = sm + 35424;   // [128][9]   1152
    float* covS  = sm + 36576;   // 81
    const float invl = 1.0f/ls[d], oscd = osc[d], qsd = sqrtf(qn[d]);
    const float4* KxzS4 = (const float4*)KxzS;
    const float4* T1S4  = (const float4*)T1S;
    const float4* xqS4  = (const float4*)xqS;
    const unsigned long long* xm_u = (const unsigned long long*)xm;

    for (int l = tid; l < 16384; l += 1024)
      KinvS[(l>>7)*129 + (l&127)] = Kinvg[d*16384 + l];
    for (int l = tid; l < 16384; l += 1024) {
      int n = l >> 7, m = l & 127;
      AT[m*129 + n] = Ag[(n*32 + d)*128 + m];
    }

    const int bb = tid >> 7, mn = tid & 127;
    float4 zr[8];
    {
      const float4* zrow = (const float4*)(zsMg + d*4096 + mn*32);
#pragma unroll
      for (int kq = 0; kq < 8; kq++) zr[kq] = zrow[kq];
    }
    const float z2m = zs2g[d*128 + mn];
    __syncthreads();

    for (int t = 1; t < 48; t++) {
      // prefetch (hidden behind the wait)
      const float v_ef = ef[((t*128 + (tid>>3))*32 + d)*8 + (tid&7)];
      const float v_eq = eq[((t*8+bb)*128 + mn)*32 + d];

      if (tid < 8) pollge(cnt + (32+tid)*16, t);
      __syncthreads();
      // stage: xq from xm, ef slice
      if (tid < 128) {
        unsigned long long u = aloadu(xm_u + tid);
        float2 f = __builtin_bit_cast(float2, u);
        int b2 = tid >> 4, k2 = (tid & 15)*2;
        xqS[b2*36 + k2]     = f.x * invl;
        xqS[b2*36 + k2 + 1] = f.y * invl;
      }
      efS[(tid>>3)*9 + (tid&7)] = v_ef;
      __syncthreads();
      { // Kxz[bb][mn]
        float dot = 0.f, sq = 0.f;
#pragma unroll
        for (int kq = 0; kq < 8; kq++) {
          float4 x4 = xqS4[bb*9+kq];
          dot += dot4f(zr[kq], x4);
          sq  += dot4f(x4, x4);
        }
        KxzS[bb*132+mn] = oscd * expf(-0.5f * fmaxf(sq + z2m - 2.f*dot, 0.f));
      }
      __syncthreads();
      float mv;
      { // fused T1[bb][mn] + mean[bb][mn] (both LDS, conflict-free)
        float t1a = 0.f, t1b = 0.f, ma = 0.f, mb2 = 0.f;
#pragma unroll 8
        for (int mm = 0; mm < 128; mm += 2) {
          float kx0 = KxzS[bb*132+mm], kx1 = KxzS[bb*132+mm+1];
          t1a = fmaf(kx0, KinvS[mm*129+mn],     t1a);
          t1b = fmaf(kx1, KinvS[(mm+1)*129+mn], t1b);
          ma  = fmaf(kx0, AT[mm*129+mn],        ma);
          mb2 = fmaf(kx1, AT[(mm+1)*129+mn],    mb2);
        }
        T1S[bb*132+mn] = t1a + t1b;
        mv = ma + mb2;
      }
      __syncthreads();
      if (tid < 64) { // cov 8x8
        int b = tid >> 3, c = tid & 7;
        float sc = 0.f, dt = 0.f, sqb = 0.f, sqc = 0.f;
#pragma unroll
        for (int mq = 0; mq < 32; mq++) sc += dot4f(T1S4[b*33+mq], KxzS4[c*33+mq]);
#pragma unroll
        for (int kq = 0; kq < 8; kq++) {
          float4 xb = xqS4[b*9+kq], xc = xqS4[c*9+kq];
          dt += dot4f(xb, xc); sqb += dot4f(xb, xb); sqc += dot4f(xc, xc);
        }
        float kxx = oscd*expf(-0.5f*fmaxf(sqb + sqc - 2.f*dt, 0.f));
        covS[b*9+c] = kxx - sc + (b==c ? JITF : 0.f);
      }
      __syncthreads();
      { // redundant per-thread chol8x8 with static-index row-bb extraction
        float Lc[8][8];
        float f = mv;
#pragma unroll
        for (int a = 0; a < 8; a++) {
          float s = covS[a*9+a];
#pragma unroll
          for (int k = 0; k < 8; k++) if (k < a) s -= Lc[a][k]*Lc[a][k];
          float la = sqrtf(s);
          Lc[a][a] = la;
          if (a == bb) f = fmaf(la, efS[mn*9+a], f);
          float ila = 1.0f / la;
#pragma unroll
          for (int i2 = 0; i2 < 8; i2++) if (i2 > a) {
            float s2 = covS[i2*9+a];
#pragma unroll
            for (int k = 0; k < 8; k++) if (k < a) s2 -= Lc[i2][k]*Lc[a][k];
            float lv = s2 * ila;
            Lc[i2][a] = lv;
            if (i2 == bb) f = fmaf(lv, efS[mn*9+a], f);
          }
        }
        f = fmaf(v_eq, qsd, f);
        astoref(Xw + (d*8+bb)*128 + mn, f);
      }
      gsignal(cnt + d*16, t, tid);
    }
    if (tid < 8) pollge(cnt + (32+tid)*16, 48);
    __syncthreads();
  } else {
    // ================= b-role =================
    const int b = blk - 32;
    float* XN     = sm;          // [128][33] 4224 (centered)
    float* Ps     = sm + 4224;   // [32][36]  1152
    float* Sinvs  = sm + 5376;   // [32][33]  1056
    float* taperS = sm + 6432;   // 1024
    float* mersS  = sm + 7456;   // [48][32]  1536
    float* rowP   = sm + 8992;   // [2][2][36] 144
    float* colP   = sm + 9136;   // 144
    float* detS   = sm + 9280;   // 16
    float* XmsS   = sm + 9296;   // 32
    float* residS = sm + 9328;   // 32
    float* miS    = sm + 9360;   // 32
    float* rsdS   = sm + 9392;   // 32
    float* rnS    = sm + 9424;   // 32
    const float4* er4 = (const float4*)er;
    const unsigned long long* Xw_u = (const unsigned long long*)Xw;

    if (tid < 1024) { // taper
      int ii = tid >> 5, jj = tid & 31;
      int ad = ii - jj; if (ad < 0) ad = -ad;
      int dist = (ad < 32 - ad) ? ad : (32 - ad);
      double z = (double)dist / 5.0;
      double z2 = z*z, z3 = z2*z, z4 = z3*z, z5 = z4*z;
      double gval;
      if (z < 1.0) gval = 1.0 - (5.0/3.0)*z2 + (5.0/8.0)*z3 + 0.5*z4 - 0.25*z5;
      else if (z < 2.0) gval = 4.0 - 5.0*z + (5.0/3.0)*z2 + (5.0/8.0)*z3 - 0.5*z4 + (1.0/12.0)*z5 - 2.0/(3.0*z);
      else gval = 0.0;
      taperS[tid] = (float)gval;
    }
    if (tid < 32) { rnS[tid] = rn[tid]; rsdS[tid] = sqrtf(rn[tid]); }
    if (tid < 384) { // mers for all t
      int tt = tid >> 3, jq = tid & 7;
      float sx = 0.f, sy = 0.f, sz = 0.f, sw = 0.f;
      for (int n = 0; n < 128; n++) {
        float4 e = er4[((tt*8+b)*128+n)*8 + jq];
        sx += e.x; sy += e.y; sz += e.z; sw += e.w;
      }
      int o = tt*32 + jq*4;
      mersS[o]   = sx*(1.f/128.f);
      mersS[o+1] = sy*(1.f/128.f);
      mersS[o+2] = sz*(1.f/128.f);
      mersS[o+3] = sw*(1.f/128.f);
    }
    __syncthreads();

    float llacc = 0.f;
    const int i = tid >> 5, j = tid & 31;
    for (int t = 0; t < 48; t++) {
      float yv = 0.f;
      if (tid < 32) yv = y[(b*48+t)*32 + tid];   // prefetch
      if (t > 0) { if (tid < 32) pollge(cnt + tid*16, t); }
      __syncthreads();
      { // load Xw; half-wave-shuffle row mean; center; write XN
        unsigned long long u0 = aloadu(Xw_u + (i*8+b)*64 + j);
        unsigned long long u1 = aloadu(Xw_u + (i*8+b)*64 + j + 32);
        float2 f0 = __builtin_bit_cast(float2, u0);
        float2 f1 = __builtin_bit_cast(float2, u1);
        float s4 = (f0.x+f0.y)+(f1.x+f1.y);
#pragma unroll
        for (int mk = 1; mk <= 16; mk <<= 1) s4 += __shfl_xor(s4, mk, 64);
        float mu = s4 * (1.f/128.f);
        if (j == 0) XmsS[i] = mu;
        XN[(2*j)*33+i]    = f0.x - mu;
        XN[(2*j+1)*33+i]  = f0.y - mu;
        XN[(2*j+64)*33+i] = f1.x - mu;
        XN[(2*j+65)*33+i] = f1.y - mu;
      }
      __syncthreads();
      float val;
      { // P[i][j] conflict-free (broadcast + consecutive)
        float a0 = 0.f, a1 = 0.f;
#pragma unroll 4
        for (int n = 0; n < 128; n += 2) {
          a0 = fmaf(XN[n*33+i],     XN[n*33+j],     a0);
          a1 = fmaf(XN[(n+1)*33+i], XN[(n+1)*33+j], a1);
        }
        float pv = taperS[i*32+j] * (a0+a1) * (1.f/127.f);
        Ps[i*36+j] = pv;
        val = pv + ((i==j) ? rnS[i] : 0.f);
      }
      // 2x2-pivot block sweep of S in registers -> val = (-Sinv)[i][j]
#pragma unroll 1
      for (int kb = 0; kb < 16; kb++) {
        int k0 = kb*2, k1 = k0+1, par = (kb&1)*72;
        if (i == k0) rowP[par + j]      = val;
        if (i == k1) rowP[par + 36 + j] = val;
        if (j == k0) colP[par + i]      = val;
        if (j == k1) colP[par + 36 + i] = val;
        __syncthreads();
        float a  = rowP[par + k0];
        float bb = rowP[par + k1];
        float c  = rowP[par + 36 + k1];
        float det = fmaf(a, c, -bb*bb);
        float idet = 1.0f/det;
        float ci0 = colP[par + i], ci1 = colP[par + 36 + i];
        float r0j = rowP[par + j], r1j = rowP[par + 36 + j];
        float w0 = (ci0*c - ci1*bb)*idet;
        float w1 = (ci1*a - ci0*bb)*idet;
        float v0 = (c*r0j - bb*r1j)*idet;
        float v1 = (a*r1j - bb*r0j)*idet;
        float nv = val - w0*r0j - w1*r1j;
        if (i == k0) nv = v0;
        if (i == k1) nv = v1;
        if (j == k0) nv = w0;
        if (j == k1) nv = w1;
        if (i == k0 && j == k0) nv = -c*idet;
        if (i == k0 && j == k1) nv =  bb*idet;
        if (i == k1 && j == k0) nv =  bb*idet;
        if (i == k1 && j == k1) nv = -a*idet;
        val = nv;
        if (tid == 0) detS[kb] = det;
      }
      Sinvs[i*33+j] = -val;
      if (tid < 32) {
        float rs = yv - XmsS[tid];
        residS[tid] = rs;
        miS[tid] = fmaf(mersS[t*32+tid], rsdS[tid], rs);
      }
      __syncthreads();
      if (tid < 32) {
        // beta = Sinv@mi; posterior via H=I identities:
        // xmp = Xms + mi - rn*beta ; var_post = rn - rn^2*Sinv_ii
        float bt = 0.f;
#pragma unroll
        for (int k = 0; k < 32; k++) bt = fmaf(Sinvs[tid*33+k], miS[k], bt);
        float xmp = XmsS[tid] + miS[tid] - rnS[tid]*bt;
        out[OFM + (b*48+t)*32 + tid] = xmp;
        out[OFV + (b*48+t)*32 + tid] = rnS[tid] - rnS[tid]*rnS[tid]*Sinvs[tid*33+tid];
        astoref(xm + b*32 + tid, xmp);
      } else if (tid < 64) {
        // alpha = Sinv@resid; ll contribution via upper-half shuffle reduce
        int ii = tid - 32;
        float al = 0.f;
#pragma unroll
        for (int k = 0; k < 32; k++) al = fmaf(Sinvs[ii*33+k], residS[k], al);
        float contrib = al * residS[ii] + ((ii < 16) ? logf(detS[ii]) : 0.f);
#pragma unroll
        for (int mk = 1; mk <= 16; mk <<= 1) contrib += __shfl_xor(contrib, mk, 64);
        if (ii == 0) {
          llacc += -0.5f*(32.f*LOG2PIF + contrib);
          if (t == 47) astoref(llb + b, llacc);
        }
      }
      gsignal(cnt + (32+b)*16, t+1, tid);
    }
    if (tid < 8) pollge(cnt + (32+tid)*16, 48);
    __syncthreads();
  }

  // ---------------- epilogue: x_final broadcast + elbo ----------------
  if (tid < 128) {
    unsigned long long u = aloadu((const unsigned long long*)xm + tid);
    float2 f = __builtin_bit_cast(float2, u);
    sm[2*tid] = f.x; sm[2*tid+1] = f.y;
  }
  __syncthreads();
  for (int v = blk*1024 + tid; v < 1048576; v += 40960)
    out[1 + v] = sm[v & 255];
  if (blk == 32 && tid == 0) {
    double ll = 0.0;
    for (int i2 = 0; i2 < 8; i2++) ll += (double)aloadf(llb + i2);
    double ldK = 0.0, tr = 0.0, mah = 0.0, ldS = 0.0;
    for (int d2 = 0; d2 < 32; d2++) {
      ldK += (double)kld[d2];
      tr  += (double)kld[32+d2];
      mah += (double)kld[64+d2];
      ldS += (double)kld[96+d2];
    }
    double klv = 0.5*(tr + mah - 4096.0 + 2.0*ldK - 2.0*ldS);
    out[0] = (float)(ll - klv/100000.0);
  }
}

extern "C" void kernel_launch(void* const* d_in, const int* in_sizes, int n_in,
                              void* d_out, int out_size, void* d_ws, size_t ws_size,
                              hipStream_t stream) {
  const float* ips = (const float*)d_in[0];
  const float* ls  = (const float*)d_in[2];
  const float* osc = (const float*)d_in[3];
  const float* qmu = (const float*)d_in[4];
  const float* qL  = (const float*)d_in[5];
  const float* qn  = (const float*)d_in[6];
  const float* rn  = (const float*)d_in[7];
  const float* x0  = (const float*)d_in[8];
  const float* y   = (const float*)d_in[9];
  const float* eu  = (const float*)d_in[10];
  const float* ef  = (const float*)d_in[11];
  const float* eq  = (const float*)d_in[12];
  const float* er  = (const float*)d_in[13];
  float* out = (float*)d_out;
  float* ws  = (float*)d_ws;

  float* w_zsm  = ws + WZSM;
  float* w_zs2  = ws + WZS2;
  float* w_kinv = ws + WKINV;
  float* w_A    = ws + WA;
  float* w_U    = ws + WU;
  float* w_Xw   = ws + WXW;
  float* w_xm   = ws + WXM;
  float* w_llb  = ws + WLLB;
  float* w_kld  = ws + WKLD;
  int*   w_cnt  = (int*)(ws + WCNT);

  k_sweep<<<32, 512, 0, stream>>>(ips, ls, osc, qL, qmu, w_zsm, w_zs2, w_kinv, w_kld, w_cnt);
  k_U<<<128, 128, 0, stream>>>(qL, qmu, eu, w_U);
  k_A2<<<128, 256, 0, stream>>>(w_kinv, w_U, w_A);
  k_t0gp<<<4096, 128, 0, stream>>>(x0, ls, osc, qn, w_zsm, w_zs2, w_kinv, w_A, ef, eq, w_Xw);
  void* args[] = { (void*)&ls, (void*)&osc, (void*)&qn, (void*)&rn, (void*)&y,
                   (void*)&ef, (void*)&eq, (void*)&er, (void*)&w_zsm, (void*)&w_zs2,
                   (void*)&w_kinv, (void*)&w_A, (void*)&w_Xw, (void*)&w_xm, (void*)&w_llb,
                   (void*)&w_kld, (void*)&out, (void*)&w_cnt };
  hipLaunchCooperativeKernel((void*)k_scan, dim3(40), dim3(1024), args, 0, stream);
}